// Round 10
// baseline (5183.392 us; speedup 1.0000x reference)
//
#include <hip/hip_runtime.h>
#include <math.h>

#define BB 16
#define HIST 8
#define PRED 12
#define NN 2000
#define NE 64000
#define FEAT 13
#define IN_DIM 14   // FEAT+1
#define HID 64
#define GNN_OUT 13
#define EH 32
#define EOUT 30
#define EOUT_PAD 32
#define TSTEPS 20   // HIST+PRED
#define EIN 31      // 2*IN_DIM + 3
#define SB 128      // stats partial blocks

typedef unsigned int uint;
typedef unsigned short ushort;

__device__ __forceinline__ float sigmoidf_(float x) {
    return __builtin_amdgcn_rcpf(1.0f + __expf(-x));
}

__device__ __forceinline__ ushort f2bf(float x) {
    uint u = __float_as_uint(x);
    u += 0x7fffu + ((u >> 16) & 1u);
    return (ushort)(u >> 16);
}

__device__ __forceinline__ float bf2f(ushort u) {
    return __uint_as_float(((uint)u) << 16);
}

__device__ __forceinline__ float bflo(uint u) { return __uint_as_float(u << 16); }
__device__ __forceinline__ float bfhi(uint u) { return __uint_as_float(u & 0xffff0000u); }
__device__ __forceinline__ uint pack2(float a, float b) {
    return (uint)f2bf(a) | ((uint)f2bf(b) << 16);
}

// ---- stats ----
__global__ __launch_bounds__(256) void stats_partial(const float* __restrict__ edge_attr,
                                                     double* __restrict__ part) {
    __shared__ double sh[256];
    int tid = threadIdx.x, bid = blockIdx.x;
    double s0 = 0, q0 = 0, s1 = 0, q1 = 0;
    for (int i = bid * 256 + tid; i < NE; i += SB * 256) {
        double d = (double)edge_attr[2 * i];
        double r = (double)edge_attr[2 * i + 1];
        s0 += d; q0 += d * d; s1 += r; q1 += r * r;
    }
    double vals[4] = {s0, q0, s1, q1};
#pragma unroll
    for (int k = 0; k < 4; ++k) {
        sh[tid] = vals[k];
        __syncthreads();
        for (int off = 128; off > 0; off >>= 1) {
            if (tid < off) sh[tid] += sh[tid + off];
            __syncthreads();
        }
        if (tid == 0) part[k * SB + bid] = sh[0];
        __syncthreads();
    }
}

__global__ __launch_bounds__(128) void stats_final(const double* __restrict__ part,
                                                   float* __restrict__ stats) {
    __shared__ double sh[128];
    int tid = threadIdx.x;
    double res[4];
#pragma unroll
    for (int k = 0; k < 4; ++k) {
        sh[tid] = part[k * SB + tid];
        __syncthreads();
        for (int off = 64; off > 0; off >>= 1) {
            if (tid < off) sh[tid] += sh[tid + off];
            __syncthreads();
        }
        res[k] = sh[0];
        __syncthreads();
    }
    if (tid == 0) {
        double n = (double)NE;
        double m0 = res[0] / n, m1 = res[2] / n;
        double v0 = (res[1] - res[0] * res[0] / n) / (n - 1.0);
        double v1 = (res[3] - res[2] * res[2] / n) / (n - 1.0);
        stats[0] = (float)m0;
        stats[1] = (float)(1.0 / sqrt(v0));
        stats[2] = (float)m1;
        stats[3] = (float)(1.0 / sqrt(v1));
    }
}

__global__ void init_xn(const float* __restrict__ pm25,
                        float* __restrict__ xn) {
    int i = blockIdx.x * 256 + threadIdx.x;
    if (i >= BB * NN) return;
    int b = i / NN, n = i % NN;
    xn[i] = pm25[(b * HIST + (HIST - 1)) * NN + n];
}

// ---- CSR build ----
__global__ void count_kernel(const int* __restrict__ edge_index,
                             int* __restrict__ degT, int* __restrict__ degS) {
    int e = blockIdx.x * 256 + threadIdx.x;
    if (e >= NE) return;
    atomicAdd(&degT[edge_index[NE + e]], 1);
    atomicAdd(&degS[edge_index[e]], 1);
}

__global__ void scan2_kernel(const int* __restrict__ degT, const int* __restrict__ degS,
                             int* __restrict__ offT, int* __restrict__ offS,
                             int* __restrict__ curT, int* __restrict__ curS) {
    const int* deg = blockIdx.x ? degS : degT;
    int* off = blockIdx.x ? offS : offT;
    int* cur = blockIdx.x ? curS : curT;
    __shared__ int part[256];
    int tid = threadIdx.x;
    int base = tid * 8;
    int v[8]; int s = 0;
#pragma unroll
    for (int k = 0; k < 8; ++k) {
        int idx = base + k;
        int d = (idx < NN) ? deg[idx] : 0;
        v[k] = d; s += d;
    }
    part[tid] = s;
    __syncthreads();
    for (int offn = 1; offn < 256; offn <<= 1) {
        int x = part[tid];
        int y = (tid >= offn) ? part[tid - offn] : 0;
        __syncthreads();
        part[tid] = x + y;
        __syncthreads();
    }
    int run = (tid > 0) ? part[tid - 1] : 0;
#pragma unroll
    for (int k = 0; k < 8; ++k) {
        int idx = base + k;
        if (idx < NN) { off[idx] = run; cur[idx] = run; }
        run += v[k];
    }
    if (tid == 255) off[NN] = run;
}

__global__ void fill_kernel(const int* __restrict__ edge_index,
                            int* __restrict__ curT, int* __restrict__ curS,
                            int* __restrict__ posT, int* __restrict__ listS_eid) {
    int e = blockIdx.x * 256 + threadIdx.x;
    if (e >= NE) return;
    int tg = edge_index[NE + e], s = edge_index[e];
    int p = atomicAdd(&curT[tg], 1);
    posT[e] = p;
    int q = atomicAdd(&curS[s], 1);
    listS_eid[q] = e;
}

__global__ void map_kernel(const int* __restrict__ listS_eid,
                           const int* __restrict__ posT,
                           int* __restrict__ listS_pos) {
    int k = blockIdx.x * 256 + threadIdx.x;
    if (k >= NE) return;
    listS_pos[k] = posT[listS_eid[k]];
}

__global__ void sort_kernel(const int* __restrict__ edge_index,
                            const float* __restrict__ edge_attr,
                            const int* __restrict__ posT,
                            int* __restrict__ srcT, int* __restrict__ tgT,
                            float* __restrict__ attrT) {
    int e = blockIdx.x * 256 + threadIdx.x;
    if (e >= NE) return;
    int p = posT[e];
    srcT[p] = edge_index[e];
    tgT[p] = edge_index[NE + e];
    attrT[2 * p]     = edge_attr[2 * e];
    attrT[2 * p + 1] = edge_attr[2 * e + 1];
}

// Ce[p][32] (bf16x2 packed) = an0*We1[28] + an1*We1[29] + be1
__global__ void ce_kernel(const float* __restrict__ attrT,
                          const float* __restrict__ stats,
                          const float* __restrict__ We1,
                          const float* __restrict__ be1,
                          uint* __restrict__ Ce) {
    int p = blockIdx.x * 256 + threadIdx.x;
    if (p >= NE) return;
    float an0 = (attrT[2 * p]     - stats[0]) * stats[1];
    float an1 = (attrT[2 * p + 1] - stats[2]) * stats[3];
    float c[EH];
#pragma unroll
    for (int j = 0; j < EH; ++j)
        c[j] = fmaf(an0, We1[28 * EH + j], fmaf(an1, We1[29 * EH + j], be1[j]));
    uint* dst = Ce + (size_t)p * 16;
#pragma unroll
    for (int q = 0; q < 16; ++q) dst[q] = pack2(c[2 * q], c[2 * q + 1]);
}

// t=0 proj: Ps/Pt in [n][b] layout
__global__ __launch_bounds__(256) void proj0_kernel(
    const float* __restrict__ xn, const float* __restrict__ feature,
    const float* __restrict__ We1,
    const float* __restrict__ wind_mean, const float* __restrict__ wind_std,
    uint* __restrict__ Ps, uint* __restrict__ Pt,
    float* __restrict__ spd3, float* __restrict__ wdirA) {
    int i = blockIdx.x * 256 + threadIdx.x;
    if (i >= BB * NN) return;
    int b = i / NN, n = i % NN;
    float x[IN_DIM];
    x[0] = xn[i];
    const float* fr = feature + ((size_t)(b * TSTEPS + HIST) * NN + n) * FEAT;
#pragma unroll
    for (int f = 0; f < FEAT; ++f) x[1 + f] = fr[f];

    float ps[EH], pt[EH];
#pragma unroll
    for (int j = 0; j < EH; ++j) { ps[j] = 0.f; pt[j] = 0.f; }
#pragma unroll
    for (int f = 0; f < IN_DIM; ++f) {
        float xv = x[f];
#pragma unroll
        for (int j = 0; j < EH; ++j) {
            ps[j] = fmaf(xv, We1[f * EH + j], ps[j]);
            pt[j] = fmaf(xv, We1[(IN_DIM + f) * EH + j], pt[j]);
        }
    }
    uint* pso = Ps + ((size_t)n * BB + b) * 16;
    uint* pto = Pt + ((size_t)n * BB + b) * 16;
#pragma unroll
    for (int q = 0; q < 16; ++q) {
        pso[q] = pack2(ps[2 * q], ps[2 * q + 1]);
        pto[q] = pack2(pt[2 * q], pt[2 * q + 1]);
    }
    spd3[n * BB + b]  = 3.0f * fmaf(x[12], wind_std[0], wind_mean[0]);
    wdirA[n * BB + b] = fmaf(x[13], wind_std[1], wind_mean[1]);
}

// edge kernel v6: thread=(p,b); [p][b] e_out layout; all-b in one launch
__global__ __launch_bounds__(256) void edge_kernel_v6(
    const uint* __restrict__ Ps, const uint* __restrict__ Pt,
    const uint* __restrict__ Ce,
    const float* __restrict__ We1,
    const float* __restrict__ We2, const float* __restrict__ be2,
    const int* __restrict__ srcT, const int* __restrict__ tgT,
    const float* __restrict__ attrT,
    const float* __restrict__ spd3, const float* __restrict__ wdirA,
    ushort* __restrict__ e_out) {
    int tid = threadIdx.x;
    int b = tid & 15;
    int p = blockIdx.x * 16 + (tid >> 4);
    int s  = srcT[p];
    int tg = tgT[p];
    float dist  = attrT[2 * p];
    float direc = attrT[2 * p + 1];
    float sp3 = spd3[s * BB + b];
    float wd  = wdirA[s * BB + b];
    float theta = fabsf(direc - wd);
    float ew = fmaxf(sp3 * cosf(theta) * __builtin_amdgcn_rcpf(dist), 0.0f);

    const uint4* ps4 = (const uint4*)(Ps + ((size_t)s  * BB + b) * 16);
    const uint4* pt4 = (const uint4*)(Pt + ((size_t)tg * BB + b) * 16);
    const uint4* ce4 = (const uint4*)(Ce + (size_t)p * 16);

    float h[EH];
#pragma unroll
    for (int q = 0; q < 4; ++q) {
        uint4 a = ps4[q], c = pt4[q], d = ce4[q];
        uint av[4] = {a.x, a.y, a.z, a.w};
        uint cv[4] = {c.x, c.y, c.z, c.w};
        uint dv[4] = {d.x, d.y, d.z, d.w};
#pragma unroll
        for (int m = 0; m < 4; ++m) {
            int j = q * 8 + m * 2;
            h[j]     = bflo(av[m]) + bflo(cv[m]) + bflo(dv[m]);
            h[j + 1] = bfhi(av[m]) + bfhi(cv[m]) + bfhi(dv[m]);
        }
    }
#pragma unroll
    for (int j = 0; j < EH; ++j)
        h[j] = sigmoidf_(fmaf(ew, We1[30 * EH + j], h[j]));

    float o[EOUT];
#pragma unroll
    for (int j = 0; j < EOUT; ++j) o[j] = be2[j];
#pragma unroll
    for (int i = 0; i < EH; ++i) {
        float x = h[i];
#pragma unroll
        for (int j = 0; j < EOUT; ++j) o[j] = fmaf(x, We2[i * EOUT + j], o[j]);
    }

    uint w[16];
#pragma unroll
    for (int j = 0; j < 15; ++j)
        w[j] = pack2(sigmoidf_(o[2 * j]), sigmoidf_(o[2 * j + 1]));
    w[15] = 0u;
    uint4* dst = (uint4*)(e_out + ((size_t)p * BB + b) * EOUT_PAD);
    dst[0] = make_uint4(w[0],  w[1],  w[2],  w[3]);
    dst[1] = make_uint4(w[4],  w[5],  w[6],  w[7]);
    dst[2] = make_uint4(w[8],  w[9],  w[10], w[11]);
    dst[3] = make_uint4(w[12], w[13], w[14], w[15]);
}

// node kernel v6: one block per node n, all 16 b; streaming 1KB row-sets
__global__ __launch_bounds__(256) void node_kernel_v6(
    const ushort* __restrict__ e_out,
    const int* __restrict__ offT, const int* __restrict__ offS,
    const int* __restrict__ listS_pos,
    float* __restrict__ xn,
    const float* __restrict__ feature,
    const float* __restrict__ Wn, const float* __restrict__ bn,
    const float* __restrict__ W1, const float* __restrict__ b1,
    const float* __restrict__ W2, const float* __restrict__ b2,
    const float* __restrict__ W3, const float* __restrict__ b3,
    const float* __restrict__ Wo, const float* __restrict__ bo,
    const float* __restrict__ We1,
    const float* __restrict__ wind_mean, const float* __restrict__ wind_std,
    uint* __restrict__ Ps, uint* __restrict__ Pt,
    float* __restrict__ spd3, float* __restrict__ wdirA,
    float* __restrict__ out, int t) {
    int n = blockIdx.x;
    int tid = threadIdx.x;
    int w = tid >> 6;        // wave 0..3
    int lane = tid & 63;
    int b = lane & 15;
    int c = lane >> 4;       // row quad 0..3 (8 bf16 cols each)
    int ht = HIST + t;

    const uint4* base4 = (const uint4*)e_out;  // row (p,b) at ((p*16+b)*4)

    float accA[8], accB[8];
#pragma unroll
    for (int i = 0; i < 8; ++i) { accA[i] = 0.f; accB[i] = 0.f; }

    // in-edges: contiguous positions
    int k0 = offT[n], k1 = offT[n + 1];
    int k = k0 + w;
    for (; k + 4 < k1; k += 8) {
        uint4 v0 = base4[((size_t)k       * BB + b) * 4 + c];
        uint4 v1 = base4[((size_t)(k + 4) * BB + b) * 4 + c];
        uint a0[4] = {v0.x, v0.y, v0.z, v0.w};
        uint a1[4] = {v1.x, v1.y, v1.z, v1.w};
#pragma unroll
        for (int m = 0; m < 4; ++m) {
            accA[2 * m]     += bflo(a0[m]);
            accA[2 * m + 1] += bfhi(a0[m]);
            accB[2 * m]     += bflo(a1[m]);
            accB[2 * m + 1] += bfhi(a1[m]);
        }
    }
    for (; k < k1; k += 4) {
        uint4 v0 = base4[((size_t)k * BB + b) * 4 + c];
        uint a0[4] = {v0.x, v0.y, v0.z, v0.w};
#pragma unroll
        for (int m = 0; m < 4; ++m) {
            accA[2 * m]     += bflo(a0[m]);
            accA[2 * m + 1] += bfhi(a0[m]);
        }
    }
    // out-edges: wave-uniform indirection to 1KB row-sets
    int q0 = offS[n], q1 = offS[n + 1];
    k = q0 + w;
    for (; k + 4 < q1; k += 8) {
        int r0 = listS_pos[k];
        int r1 = listS_pos[k + 4];
        uint4 v0 = base4[((size_t)r0 * BB + b) * 4 + c];
        uint4 v1 = base4[((size_t)r1 * BB + b) * 4 + c];
        uint a0[4] = {v0.x, v0.y, v0.z, v0.w};
        uint a1[4] = {v1.x, v1.y, v1.z, v1.w};
#pragma unroll
        for (int m = 0; m < 4; ++m) {
            accA[2 * m]     -= bflo(a0[m]);
            accA[2 * m + 1] -= bfhi(a0[m]);
            accB[2 * m]     -= bflo(a1[m]);
            accB[2 * m + 1] -= bfhi(a1[m]);
        }
    }
    for (; k < q1; k += 4) {
        int r0 = listS_pos[k];
        uint4 v0 = base4[((size_t)r0 * BB + b) * 4 + c];
        uint a0[4] = {v0.x, v0.y, v0.z, v0.w};
#pragma unroll
        for (int m = 0; m < 4; ++m) {
            accA[2 * m]     -= bflo(a0[m]);
            accA[2 * m + 1] -= bfhi(a0[m]);
        }
    }

    __shared__ float smAcc[4][16][36];   // pad 36: <=2-way bank alias
    __shared__ float smAgg[16][36];
    __shared__ float smHin[16][28];
    __shared__ float smH[16][HID];

#pragma unroll
    for (int i = 0; i < 8; ++i) smAcc[w][b][c * 8 + i] = accA[i] + accB[i];
    __syncthreads();

    {   // reduce over waves: 512 values, each thread handles 2
        int col = tid & 31, bb = tid >> 5;
        smAgg[bb][col] = smAcc[0][bb][col] + smAcc[1][bb][col]
                       + smAcc[2][bb][col] + smAcc[3][bb][col];
        int b2 = bb + 8;
        smAgg[b2][col] = smAcc[0][b2][col] + smAcc[1][b2][col]
                       + smAcc[2][b2][col] + smAcc[3][b2][col];
    }
    __syncthreads();

    // MLP: 4 passes, wave w handles batch bb = pass*4 + w
#pragma unroll
    for (int pass = 0; pass < 4; ++pass) {
        int bb = pass * 4 + w;
        const float* fr = feature + ((size_t)(bb * TSTEPS + ht) * NN + n) * FEAT;
        if (lane < GNN_OUT) {
            float g = bn[lane];
#pragma unroll
            for (int kk = 0; kk < EOUT; ++kk)
                g = fmaf(smAgg[bb][kk], Wn[kk * GNN_OUT + lane], g);
            smHin[bb][lane] = sigmoidf_(g);
        } else if (lane < GNN_OUT + IN_DIM) {
            smHin[bb][lane] = (lane == GNN_OUT) ? xn[bb * NN + n]
                                                : fr[lane - GNN_OUT - 1];
        }
        __syncthreads();

        float v = b1[lane];
#pragma unroll
        for (int kk = 0; kk < GNN_OUT + IN_DIM; ++kk)
            v = fmaf(smHin[bb][kk], W1[kk * HID + lane], v);
        float hval = sigmoidf_(v);
        smH[bb][lane] = hval;
        __syncthreads();

        v = b2[lane];
#pragma unroll
        for (int kk = 0; kk < HID; ++kk)
            v = fmaf(smH[bb][kk], W2[kk * HID + lane], v);
        hval = sigmoidf_(v);
        __syncthreads();
        smH[bb][lane] = hval;
        __syncthreads();

        v = b3[lane];
#pragma unroll
        for (int kk = 0; kk < HID; ++kk)
            v = fmaf(smH[bb][kk], W3[kk * HID + lane], v);
        hval = sigmoidf_(v);

        float partial = hval * Wo[lane];
#pragma unroll
        for (int m = 32; m >= 1; m >>= 1)
            partial += __shfl_xor(partial, m);
        float rr = partial + bo[0];
        if (lane == 0) {
            out[((size_t)(bb * PRED + t)) * NN + n] = rr;
            xn[bb * NN + n] = rr;
        }

        // fused proj for t+1
        if (t < PRED - 1) {
            const float* fr2 = feature + ((size_t)(bb * TSTEPS + ht + 1) * NN + n) * FEAT;
            float xv[IN_DIM];
            xv[0] = rr;
#pragma unroll
            for (int f = 0; f < FEAT; ++f) xv[1 + f] = fr2[f];
            int j = lane & 31;
            int rowbase = (lane < 32) ? 0 : IN_DIM;
            float p = 0.0f;
#pragma unroll
            for (int f = 0; f < IN_DIM; ++f)
                p = fmaf(xv[f], We1[(rowbase + f) * EH + j], p);
            float pp = __shfl_xor(p, 1);
            if (!(j & 1)) {
                uint packed = pack2(p, pp);
                uint* dst = (lane < 32 ? Ps : Pt) + ((size_t)n * BB + bb) * 16;
                dst[j >> 1] = packed;
            }
            if (lane == 0) {
                spd3[n * BB + bb]  = 3.0f * fmaf(xv[12], wind_std[0], wind_mean[0]);
                wdirA[n * BB + bb] = fmaf(xv[13], wind_std[1], wind_mean[1]);
            }
        }
        __syncthreads();
    }
}

// ================= v2 path (smallest-ws fallback, [b][p] layout) =============
__device__ __forceinline__ void compute_edge(
    int b, int e, int t,
    const float* __restrict__ xn, const float* __restrict__ feature,
    const float* __restrict__ edge_attr, const int* __restrict__ edge_index,
    const float* __restrict__ stats,
    const float* __restrict__ wind_mean, const float* __restrict__ wind_std,
    const float* __restrict__ We1, const float* __restrict__ be1,
    const float* __restrict__ We2, const float* __restrict__ be2,
    float* __restrict__ o) {
    int s  = edge_index[e];
    int tg = edge_index[NE + e];
    int ht = HIST + t;
    const float* fs  = feature + ((size_t)(b * TSTEPS + ht) * NN + s)  * FEAT;
    const float* ftg = feature + ((size_t)(b * TSTEPS + ht) * NN + tg) * FEAT;
    float ev[EIN];
    ev[0] = xn[b * NN + s];
#pragma unroll
    for (int f = 0; f < FEAT; ++f) ev[1 + f] = fs[f];
    ev[14] = xn[b * NN + tg];
#pragma unroll
    for (int f = 0; f < FEAT; ++f) ev[15 + f] = ftg[f];
    float dist  = edge_attr[2 * e];
    float direc = edge_attr[2 * e + 1];
    ev[28] = (dist  - stats[0]) * stats[1];
    ev[29] = (direc - stats[2]) * stats[3];
    float speed = ev[12] * wind_std[0] + wind_mean[0];
    float wdir  = ev[13] * wind_std[1] + wind_mean[1];
    float theta = fabsf(direc - wdir);
    float ew    = 3.0f * speed * cosf(theta) / dist;
    ev[30] = fmaxf(ew, 0.0f);
    float h[EH];
#pragma unroll
    for (int j = 0; j < EH; ++j) h[j] = be1[j];
#pragma unroll
    for (int i = 0; i < EIN; ++i) {
        float x = ev[i];
#pragma unroll
        for (int j = 0; j < EH; ++j) h[j] = fmaf(x, We1[i * EH + j], h[j]);
    }
#pragma unroll
    for (int j = 0; j < EH; ++j) h[j] = sigmoidf_(h[j]);
#pragma unroll
    for (int j = 0; j < EOUT; ++j) o[j] = be2[j];
#pragma unroll
    for (int i = 0; i < EH; ++i) {
        float x = h[i];
#pragma unroll
        for (int j = 0; j < EOUT; ++j) o[j] = fmaf(x, We2[i * EOUT + j], o[j]);
    }
}

__global__ __launch_bounds__(256) void edge_kernel_v2(
    const float* __restrict__ xn, const float* __restrict__ feature,
    const float* __restrict__ edge_attr, const int* __restrict__ edge_index,
    const float* __restrict__ stats,
    const float* __restrict__ wind_mean, const float* __restrict__ wind_std,
    const float* __restrict__ We1, const float* __restrict__ be1,
    const float* __restrict__ We2, const float* __restrict__ be2,
    const int* __restrict__ posT,
    ushort* __restrict__ e_out, int t) {
    int e = blockIdx.x * 256 + threadIdx.x;
    if (e >= NE) return;
    int b = blockIdx.y;
    float o[EOUT];
    compute_edge(b, e, t, xn, feature, edge_attr, edge_index, stats,
                 wind_mean, wind_std, We1, be1, We2, be2, o);
    uint w[16];
#pragma unroll
    for (int j = 0; j < 15; ++j)
        w[j] = pack2(sigmoidf_(o[2 * j]), sigmoidf_(o[2 * j + 1]));
    w[15] = 0u;
    int row = posT[e];
    uint4* dst = (uint4*)(e_out + ((size_t)b * NE + (size_t)row) * EOUT_PAD);
    dst[0] = make_uint4(w[0],  w[1],  w[2],  w[3]);
    dst[1] = make_uint4(w[4],  w[5],  w[6],  w[7]);
    dst[2] = make_uint4(w[8],  w[9],  w[10], w[11]);
    dst[3] = make_uint4(w[12], w[13], w[14], w[15]);
}

__global__ __launch_bounds__(256) void node_kernel_v2(
    const ushort* __restrict__ e_out,
    const int* __restrict__ offT, const int* __restrict__ offS,
    const int* __restrict__ listS_pos,
    float* __restrict__ xn,
    const float* __restrict__ feature,
    const float* __restrict__ Wn, const float* __restrict__ bn,
    const float* __restrict__ W1, const float* __restrict__ b1,
    const float* __restrict__ W2, const float* __restrict__ b2,
    const float* __restrict__ W3, const float* __restrict__ b3,
    const float* __restrict__ Wo, const float* __restrict__ bo,
    float* __restrict__ out, int t) {
    int i = blockIdx.x * 256 + threadIdx.x;
    if (i >= BB * NN) return;
    int b = i / NN, n = i % NN;
    int ht = HIST + t;
    const ushort* base = e_out + (size_t)b * NE * EOUT_PAD;
    float agg[EOUT];
#pragma unroll
    for (int j = 0; j < EOUT; ++j) agg[j] = 0.0f;
    int k0 = offT[n], k1 = offT[n + 1];
    for (int k = k0; k < k1; ++k) {
        const ushort* rr = base + (size_t)k * EOUT_PAD;
#pragma unroll
        for (int j = 0; j < EOUT; ++j) agg[j] += bf2f(rr[j]);
    }
    int q0 = offS[n], q1 = offS[n + 1];
    for (int k = q0; k < q1; ++k) {
        const ushort* rr = base + (size_t)listS_pos[k] * EOUT_PAD;
#pragma unroll
        for (int j = 0; j < EOUT; ++j) agg[j] -= bf2f(rr[j]);
    }
    float g[GNN_OUT];
#pragma unroll
    for (int j = 0; j < GNN_OUT; ++j) g[j] = bn[j];
#pragma unroll
    for (int k = 0; k < EOUT; ++k) {
        float x = agg[k];
#pragma unroll
        for (int j = 0; j < GNN_OUT; ++j) g[j] = fmaf(x, Wn[k * GNN_OUT + j], g[j]);
    }
    float hin[GNN_OUT + IN_DIM];
#pragma unroll
    for (int j = 0; j < GNN_OUT; ++j) hin[j] = sigmoidf_(g[j]);
    hin[GNN_OUT] = xn[i];
    const float* fr = feature + ((size_t)(b * TSTEPS + ht) * NN + n) * FEAT;
#pragma unroll
    for (int f = 0; f < FEAT; ++f) hin[GNN_OUT + 1 + f] = fr[f];
    float h1[HID];
#pragma unroll
    for (int j = 0; j < HID; ++j) h1[j] = b1[j];
#pragma unroll
    for (int k = 0; k < GNN_OUT + IN_DIM; ++k) {
        float x = hin[k];
#pragma unroll
        for (int j = 0; j < HID; ++j) h1[j] = fmaf(x, W1[k * HID + j], h1[j]);
    }
#pragma unroll
    for (int j = 0; j < HID; ++j) h1[j] = sigmoidf_(h1[j]);
    float h2[HID];
#pragma unroll
    for (int j = 0; j < HID; ++j) h2[j] = b2[j];
#pragma unroll
    for (int k = 0; k < HID; ++k) {
        float x = h1[k];
#pragma unroll
        for (int j = 0; j < HID; ++j) h2[j] = fmaf(x, W2[k * HID + j], h2[j]);
    }
#pragma unroll
    for (int j = 0; j < HID; ++j) h2[j] = sigmoidf_(h2[j]);
#pragma unroll
    for (int j = 0; j < HID; ++j) h1[j] = b3[j];
#pragma unroll
    for (int k = 0; k < HID; ++k) {
        float x = h2[k];
#pragma unroll
        for (int j = 0; j < HID; ++j) h1[j] = fmaf(x, W3[k * HID + j], h1[j]);
    }
    float acc = bo[0];
#pragma unroll
    for (int j = 0; j < HID; ++j) acc = fmaf(sigmoidf_(h1[j]), Wo[j], acc);
    out[((size_t)(b * PRED + t)) * NN + n] = acc;
    xn[i] = acc;
}

extern "C" void kernel_launch(void* const* d_in, const int* in_sizes, int n_in,
                              void* d_out, int out_size, void* d_ws, size_t ws_size,
                              hipStream_t stream) {
    const float* pm25      = (const float*)d_in[0];
    const float* feature   = (const float*)d_in[1];
    const float* edge_attr = (const float*)d_in[2];
    const float* wind_mean = (const float*)d_in[3];
    const float* wind_std  = (const float*)d_in[4];
    const float* We1 = (const float*)d_in[5];
    const float* be1 = (const float*)d_in[6];
    const float* We2 = (const float*)d_in[7];
    const float* be2 = (const float*)d_in[8];
    const float* Wn  = (const float*)d_in[9];
    const float* bn  = (const float*)d_in[10];
    const float* W1  = (const float*)d_in[11];
    const float* b1  = (const float*)d_in[12];
    const float* W2  = (const float*)d_in[13];
    const float* b2  = (const float*)d_in[14];
    const float* W3  = (const float*)d_in[15];
    const float* b3  = (const float*)d_in[16];
    const float* Wo  = (const float*)d_in[17];
    const float* bo  = (const float*)d_in[18];
    const int* edge_index = (const int*)d_in[19];
    float* out = (float*)d_out;

    char* ws = (char*)d_ws;
    size_t off = 0;
    auto alloc = [&](size_t bytes) {
        void* p = ws + off;
        off = (off + bytes + 255) & ~(size_t)255;
        return p;
    };
    float*  xn    = (float*)alloc((size_t)BB * NN * sizeof(float));
    float*  stats = (float*)alloc(4 * sizeof(float));
    double* part  = (double*)alloc(4 * SB * sizeof(double));
    int* degT      = (int*)alloc(NN * sizeof(int));
    int* degS      = (int*)alloc(NN * sizeof(int));
    int* offT      = (int*)alloc((NN + 1) * sizeof(int));
    int* offS      = (int*)alloc((NN + 1) * sizeof(int));
    int* curT      = (int*)alloc(NN * sizeof(int));
    int* curS      = (int*)alloc(NN * sizeof(int));
    int* posT      = (int*)alloc(NE * sizeof(int));
    int* listS_eid = (int*)alloc(NE * sizeof(int));
    int* listS_pos = (int*)alloc(NE * sizeof(int));
    size_t v2_mark = off;
    int*   srcT  = (int*)alloc(NE * sizeof(int));
    int*   tgT   = (int*)alloc(NE * sizeof(int));
    float* attrT = (float*)alloc(2 * NE * sizeof(float));
    uint*  Ce    = (uint*)alloc((size_t)NE * 16 * sizeof(uint));
    uint*  Ps    = (uint*)alloc((size_t)NN * BB * 16 * sizeof(uint));
    uint*  Pt    = (uint*)alloc((size_t)NN * BB * 16 * sizeof(uint));
    float* spd3  = (float*)alloc((size_t)NN * BB * sizeof(float));
    float* wdirA = (float*)alloc((size_t)NN * BB * sizeof(float));
    size_t base_off = off;
    size_t eout_bytes = (size_t)NE * BB * EOUT_PAD * sizeof(ushort);  // 65.5 MB

    bool v6 = (ws_size >= base_off + eout_bytes);
    ushort* e_out = v6 ? (ushort*)(ws + base_off) : (ushort*)(ws + v2_mark);

    stats_partial<<<SB, 256, 0, stream>>>(edge_attr, part);
    stats_final<<<1, 128, 0, stream>>>(part, stats);
    init_xn<<<(BB * NN + 255) / 256, 256, 0, stream>>>(pm25, xn);
    hipMemsetAsync(degT, 0, NN * sizeof(int), stream);
    hipMemsetAsync(degS, 0, NN * sizeof(int), stream);
    count_kernel<<<(NE + 255) / 256, 256, 0, stream>>>(edge_index, degT, degS);
    scan2_kernel<<<2, 256, 0, stream>>>(degT, degS, offT, offS, curT, curS);
    fill_kernel<<<(NE + 255) / 256, 256, 0, stream>>>(edge_index, curT, curS,
                                                      posT, listS_eid);
    map_kernel<<<(NE + 255) / 256, 256, 0, stream>>>(listS_eid, posT, listS_pos);

    if (v6) {
        sort_kernel<<<(NE + 255) / 256, 256, 0, stream>>>(edge_index, edge_attr, posT,
                                                          srcT, tgT, attrT);
        ce_kernel<<<(NE + 255) / 256, 256, 0, stream>>>(attrT, stats, We1, be1, Ce);
        proj0_kernel<<<(BB * NN + 255) / 256, 256, 0, stream>>>(
            xn, feature, We1, wind_mean, wind_std, Ps, Pt, spd3, wdirA);
        for (int t = 0; t < PRED; ++t) {
            edge_kernel_v6<<<NE / 16, 256, 0, stream>>>(Ps, Pt, Ce, We1, We2, be2,
                                                        srcT, tgT, attrT,
                                                        spd3, wdirA, e_out);
            node_kernel_v6<<<NN, 256, 0, stream>>>(
                e_out, offT, offS, listS_pos, xn, feature,
                Wn, bn, W1, b1, W2, b2, W3, b3, Wo, bo,
                We1, wind_mean, wind_std, Ps, Pt, spd3, wdirA, out, t);
        }
    } else {
        for (int t = 0; t < PRED; ++t) {
            dim3 eg((NE + 255) / 256, BB);
            edge_kernel_v2<<<eg, 256, 0, stream>>>(xn, feature, edge_attr, edge_index,
                                                   stats, wind_mean, wind_std,
                                                   We1, be1, We2, be2, posT, e_out, t);
            node_kernel_v2<<<(BB * NN + 255) / 256, 256, 0, stream>>>(
                e_out, offT, offS, listS_pos, xn, feature,
                Wn, bn, W1, b1, W2, b2, W3, b3, Wo, bo, out, t);
        }
    }
}

// Round 11
// 1727.754 us; speedup vs baseline: 3.0001x; 3.0001x over previous
//
#include <hip/hip_runtime.h>
#include <math.h>

#define BB 16
#define HIST 8
#define PRED 12
#define NN 2000
#define NE 64000
#define FEAT 13
#define IN_DIM 14   // FEAT+1
#define HID 64
#define GNN_OUT 13
#define EH 32
#define EOUT 30
#define EOUT_PAD 32
#define TSTEPS 20   // HIST+PRED
#define EIN 31      // 2*IN_DIM + 3
#define SB 128      // stats partial blocks

typedef unsigned int uint;
typedef unsigned short ushort;

__device__ __forceinline__ float sigmoidf_(float x) {
    return __builtin_amdgcn_rcpf(1.0f + __expf(-x));
}

__device__ __forceinline__ ushort f2bf(float x) {
    uint u = __float_as_uint(x);
    u += 0x7fffu + ((u >> 16) & 1u);
    return (ushort)(u >> 16);
}

__device__ __forceinline__ float bf2f(ushort u) {
    return __uint_as_float(((uint)u) << 16);
}

__device__ __forceinline__ float bflo(uint u) { return __uint_as_float(u << 16); }
__device__ __forceinline__ float bfhi(uint u) { return __uint_as_float(u & 0xffff0000u); }
__device__ __forceinline__ uint pack2(float a, float b) {
    return (uint)f2bf(a) | ((uint)f2bf(b) << 16);
}

// ---- stats ----
__global__ __launch_bounds__(256) void stats_partial(const float* __restrict__ edge_attr,
                                                     double* __restrict__ part) {
    __shared__ double sh[256];
    int tid = threadIdx.x, bid = blockIdx.x;
    double s0 = 0, q0 = 0, s1 = 0, q1 = 0;
    for (int i = bid * 256 + tid; i < NE; i += SB * 256) {
        double d = (double)edge_attr[2 * i];
        double r = (double)edge_attr[2 * i + 1];
        s0 += d; q0 += d * d; s1 += r; q1 += r * r;
    }
    double vals[4] = {s0, q0, s1, q1};
#pragma unroll
    for (int k = 0; k < 4; ++k) {
        sh[tid] = vals[k];
        __syncthreads();
        for (int off = 128; off > 0; off >>= 1) {
            if (tid < off) sh[tid] += sh[tid + off];
            __syncthreads();
        }
        if (tid == 0) part[k * SB + bid] = sh[0];
        __syncthreads();
    }
}

__global__ __launch_bounds__(128) void stats_final(const double* __restrict__ part,
                                                   float* __restrict__ stats) {
    __shared__ double sh[128];
    int tid = threadIdx.x;
    double res[4];
#pragma unroll
    for (int k = 0; k < 4; ++k) {
        sh[tid] = part[k * SB + tid];
        __syncthreads();
        for (int off = 64; off > 0; off >>= 1) {
            if (tid < off) sh[tid] += sh[tid + off];
            __syncthreads();
        }
        res[k] = sh[0];
        __syncthreads();
    }
    if (tid == 0) {
        double n = (double)NE;
        double m0 = res[0] / n, m1 = res[2] / n;
        double v0 = (res[1] - res[0] * res[0] / n) / (n - 1.0);
        double v1 = (res[3] - res[2] * res[2] / n) / (n - 1.0);
        stats[0] = (float)m0;
        stats[1] = (float)(1.0 / sqrt(v0));
        stats[2] = (float)m1;
        stats[3] = (float)(1.0 / sqrt(v1));
    }
}

__global__ void init_xn(const float* __restrict__ pm25,
                        float* __restrict__ xn) {
    int i = blockIdx.x * 256 + threadIdx.x;
    if (i >= BB * NN) return;
    int b = i / NN, n = i % NN;
    xn[i] = pm25[(b * HIST + (HIST - 1)) * NN + n];
}

// ---- CSR build ----
__global__ void count_kernel(const int* __restrict__ edge_index,
                             int* __restrict__ degT, int* __restrict__ degS) {
    int e = blockIdx.x * 256 + threadIdx.x;
    if (e >= NE) return;
    atomicAdd(&degT[edge_index[NE + e]], 1);
    atomicAdd(&degS[edge_index[e]], 1);
}

__global__ void scan2_kernel(const int* __restrict__ degT, const int* __restrict__ degS,
                             int* __restrict__ offT, int* __restrict__ offS,
                             int* __restrict__ curT, int* __restrict__ curS) {
    const int* deg = blockIdx.x ? degS : degT;
    int* off = blockIdx.x ? offS : offT;
    int* cur = blockIdx.x ? curS : curT;
    __shared__ int part[256];
    int tid = threadIdx.x;
    int base = tid * 8;
    int v[8]; int s = 0;
#pragma unroll
    for (int k = 0; k < 8; ++k) {
        int idx = base + k;
        int d = (idx < NN) ? deg[idx] : 0;
        v[k] = d; s += d;
    }
    part[tid] = s;
    __syncthreads();
    for (int offn = 1; offn < 256; offn <<= 1) {
        int x = part[tid];
        int y = (tid >= offn) ? part[tid - offn] : 0;
        __syncthreads();
        part[tid] = x + y;
        __syncthreads();
    }
    int run = (tid > 0) ? part[tid - 1] : 0;
#pragma unroll
    for (int k = 0; k < 8; ++k) {
        int idx = base + k;
        if (idx < NN) { off[idx] = run; cur[idx] = run; }
        run += v[k];
    }
    if (tid == 255) off[NN] = run;
}

__global__ void fill_kernel(const int* __restrict__ edge_index,
                            int* __restrict__ curT, int* __restrict__ curS,
                            int* __restrict__ posT, int* __restrict__ listS_eid) {
    int e = blockIdx.x * 256 + threadIdx.x;
    if (e >= NE) return;
    int tg = edge_index[NE + e], s = edge_index[e];
    int p = atomicAdd(&curT[tg], 1);
    posT[e] = p;
    int q = atomicAdd(&curS[s], 1);
    listS_eid[q] = e;
}

__global__ void map_kernel(const int* __restrict__ listS_eid,
                           const int* __restrict__ posT,
                           int* __restrict__ listS_pos) {
    int k = blockIdx.x * 256 + threadIdx.x;
    if (k >= NE) return;
    listS_pos[k] = posT[listS_eid[k]];
}

__global__ void sort_kernel(const int* __restrict__ edge_index,
                            const float* __restrict__ edge_attr,
                            const int* __restrict__ posT,
                            int* __restrict__ srcT, int* __restrict__ tgT,
                            float* __restrict__ attrT) {
    int e = blockIdx.x * 256 + threadIdx.x;
    if (e >= NE) return;
    int p = posT[e];
    srcT[p] = edge_index[e];
    tgT[p] = edge_index[NE + e];
    attrT[2 * p]     = edge_attr[2 * e];
    attrT[2 * p + 1] = edge_attr[2 * e + 1];
}

// Ce[p][32] (bf16x2 packed) = an0*We1[28] + an1*We1[29] + be1
__global__ void ce_kernel(const float* __restrict__ attrT,
                          const float* __restrict__ stats,
                          const float* __restrict__ We1,
                          const float* __restrict__ be1,
                          uint* __restrict__ Ce) {
    int p = blockIdx.x * 256 + threadIdx.x;
    if (p >= NE) return;
    float an0 = (attrT[2 * p]     - stats[0]) * stats[1];
    float an1 = (attrT[2 * p + 1] - stats[2]) * stats[3];
    float c[EH];
#pragma unroll
    for (int j = 0; j < EH; ++j)
        c[j] = fmaf(an0, We1[28 * EH + j], fmaf(an1, We1[29 * EH + j], be1[j]));
    uint* dst = Ce + (size_t)p * 16;
#pragma unroll
    for (int q = 0; q < 16; ++q) dst[q] = pack2(c[2 * q], c[2 * q + 1]);
}

// t=0 proj: Ps/Pt in [n][b] layout
__global__ __launch_bounds__(256) void proj0_kernel(
    const float* __restrict__ xn, const float* __restrict__ feature,
    const float* __restrict__ We1,
    const float* __restrict__ wind_mean, const float* __restrict__ wind_std,
    uint* __restrict__ Ps, uint* __restrict__ Pt,
    float* __restrict__ spd3, float* __restrict__ wdirA) {
    int i = blockIdx.x * 256 + threadIdx.x;
    if (i >= BB * NN) return;
    int b = i / NN, n = i % NN;
    float x[IN_DIM];
    x[0] = xn[i];
    const float* fr = feature + ((size_t)(b * TSTEPS + HIST) * NN + n) * FEAT;
#pragma unroll
    for (int f = 0; f < FEAT; ++f) x[1 + f] = fr[f];

    float ps[EH], pt[EH];
#pragma unroll
    for (int j = 0; j < EH; ++j) { ps[j] = 0.f; pt[j] = 0.f; }
#pragma unroll
    for (int f = 0; f < IN_DIM; ++f) {
        float xv = x[f];
#pragma unroll
        for (int j = 0; j < EH; ++j) {
            ps[j] = fmaf(xv, We1[f * EH + j], ps[j]);
            pt[j] = fmaf(xv, We1[(IN_DIM + f) * EH + j], pt[j]);
        }
    }
    uint* pso = Ps + ((size_t)n * BB + b) * 16;
    uint* pto = Pt + ((size_t)n * BB + b) * 16;
#pragma unroll
    for (int q = 0; q < 16; ++q) {
        pso[q] = pack2(ps[2 * q], ps[2 * q + 1]);
        pto[q] = pack2(pt[2 * q], pt[2 * q + 1]);
    }
    spd3[n * BB + b]  = 3.0f * fmaf(x[12], wind_std[0], wind_mean[0]);
    wdirA[n * BB + b] = fmaf(x[13], wind_std[1], wind_mean[1]);
}

// edge kernel v6: thread=(p,b); [p][b] e_out layout; all-b in one launch
__global__ __launch_bounds__(256) void edge_kernel_v6(
    const uint* __restrict__ Ps, const uint* __restrict__ Pt,
    const uint* __restrict__ Ce,
    const float* __restrict__ We1,
    const float* __restrict__ We2, const float* __restrict__ be2,
    const int* __restrict__ srcT, const int* __restrict__ tgT,
    const float* __restrict__ attrT,
    const float* __restrict__ spd3, const float* __restrict__ wdirA,
    ushort* __restrict__ e_out) {
    int tid = threadIdx.x;
    int b = tid & 15;
    int p = blockIdx.x * 16 + (tid >> 4);
    int s  = srcT[p];
    int tg = tgT[p];
    float dist  = attrT[2 * p];
    float direc = attrT[2 * p + 1];
    float sp3 = spd3[s * BB + b];
    float wd  = wdirA[s * BB + b];
    float theta = fabsf(direc - wd);
    float ew = fmaxf(sp3 * cosf(theta) * __builtin_amdgcn_rcpf(dist), 0.0f);

    const uint4* ps4 = (const uint4*)(Ps + ((size_t)s  * BB + b) * 16);
    const uint4* pt4 = (const uint4*)(Pt + ((size_t)tg * BB + b) * 16);
    const uint4* ce4 = (const uint4*)(Ce + (size_t)p * 16);

    float h[EH];
#pragma unroll
    for (int q = 0; q < 4; ++q) {
        uint4 a = ps4[q], c = pt4[q], d = ce4[q];
        uint av[4] = {a.x, a.y, a.z, a.w};
        uint cv[4] = {c.x, c.y, c.z, c.w};
        uint dv[4] = {d.x, d.y, d.z, d.w};
#pragma unroll
        for (int m = 0; m < 4; ++m) {
            int j = q * 8 + m * 2;
            h[j]     = bflo(av[m]) + bflo(cv[m]) + bflo(dv[m]);
            h[j + 1] = bfhi(av[m]) + bfhi(cv[m]) + bfhi(dv[m]);
        }
    }
#pragma unroll
    for (int j = 0; j < EH; ++j)
        h[j] = sigmoidf_(fmaf(ew, We1[30 * EH + j], h[j]));

    float o[EOUT];
#pragma unroll
    for (int j = 0; j < EOUT; ++j) o[j] = be2[j];
#pragma unroll
    for (int i = 0; i < EH; ++i) {
        float x = h[i];
#pragma unroll
        for (int j = 0; j < EOUT; ++j) o[j] = fmaf(x, We2[i * EOUT + j], o[j]);
    }

    uint w[16];
#pragma unroll
    for (int j = 0; j < 15; ++j)
        w[j] = pack2(sigmoidf_(o[2 * j]), sigmoidf_(o[2 * j + 1]));
    w[15] = 0u;
    uint4* dst = (uint4*)(e_out + ((size_t)p * BB + b) * EOUT_PAD);
    dst[0] = make_uint4(w[0],  w[1],  w[2],  w[3]);
    dst[1] = make_uint4(w[4],  w[5],  w[6],  w[7]);
    dst[2] = make_uint4(w[8],  w[9],  w[10], w[11]);
    dst[3] = make_uint4(w[12], w[13], w[14], w[15]);
}

// agg kernel: block per node n; coalesced 1KB-granule gather; writes agg[n][b][32]
__global__ __launch_bounds__(256) void agg_kernel(
    const ushort* __restrict__ e_out,
    const int* __restrict__ offT, const int* __restrict__ offS,
    const int* __restrict__ listS_pos,
    float* __restrict__ agg) {
    int n = blockIdx.x;
    int tid = threadIdx.x;
    int w = tid >> 6;        // wave 0..3
    int lane = tid & 63;
    int b = lane & 15;
    int c = lane >> 4;       // row quad (8 bf16 cols)

    const uint4* base4 = (const uint4*)e_out;

    float accA[8], accB[8];
#pragma unroll
    for (int i = 0; i < 8; ++i) { accA[i] = 0.f; accB[i] = 0.f; }

    int k0 = offT[n], k1 = offT[n + 1];
    int k = k0 + w;
    for (; k + 4 < k1; k += 8) {
        uint4 v0 = base4[((size_t)k       * BB + b) * 4 + c];
        uint4 v1 = base4[((size_t)(k + 4) * BB + b) * 4 + c];
        uint a0[4] = {v0.x, v0.y, v0.z, v0.w};
        uint a1[4] = {v1.x, v1.y, v1.z, v1.w};
#pragma unroll
        for (int m = 0; m < 4; ++m) {
            accA[2 * m]     += bflo(a0[m]);
            accA[2 * m + 1] += bfhi(a0[m]);
            accB[2 * m]     += bflo(a1[m]);
            accB[2 * m + 1] += bfhi(a1[m]);
        }
    }
    for (; k < k1; k += 4) {
        uint4 v0 = base4[((size_t)k * BB + b) * 4 + c];
        uint a0[4] = {v0.x, v0.y, v0.z, v0.w};
#pragma unroll
        for (int m = 0; m < 4; ++m) {
            accA[2 * m]     += bflo(a0[m]);
            accA[2 * m + 1] += bfhi(a0[m]);
        }
    }
    int q0 = offS[n], q1 = offS[n + 1];
    k = q0 + w;
    for (; k + 4 < q1; k += 8) {
        int r0 = listS_pos[k];
        int r1 = listS_pos[k + 4];
        uint4 v0 = base4[((size_t)r0 * BB + b) * 4 + c];
        uint4 v1 = base4[((size_t)r1 * BB + b) * 4 + c];
        uint a0[4] = {v0.x, v0.y, v0.z, v0.w};
        uint a1[4] = {v1.x, v1.y, v1.z, v1.w};
#pragma unroll
        for (int m = 0; m < 4; ++m) {
            accA[2 * m]     -= bflo(a0[m]);
            accA[2 * m + 1] -= bfhi(a0[m]);
            accB[2 * m]     -= bflo(a1[m]);
            accB[2 * m + 1] -= bfhi(a1[m]);
        }
    }
    for (; k < q1; k += 4) {
        int r0 = listS_pos[k];
        uint4 v0 = base4[((size_t)r0 * BB + b) * 4 + c];
        uint a0[4] = {v0.x, v0.y, v0.z, v0.w};
#pragma unroll
        for (int m = 0; m < 4; ++m) {
            accA[2 * m]     -= bflo(a0[m]);
            accA[2 * m + 1] -= bfhi(a0[m]);
        }
    }

    __shared__ float smAcc[4][16][36];   // pad 36: <=2-way bank alias
#pragma unroll
    for (int i = 0; i < 8; ++i) smAcc[w][b][c * 8 + i] = accA[i] + accB[i];
    __syncthreads();

    int col = tid & 31, bb = tid >> 5;   // bb 0..7
    float v1r = smAcc[0][bb][col] + smAcc[1][bb][col]
              + smAcc[2][bb][col] + smAcc[3][bb][col];
    agg[((size_t)n * BB + bb) * 32 + col] = v1r;
    int b2 = bb + 8;
    float v2r = smAcc[0][b2][col] + smAcc[1][b2][col]
              + smAcc[2][b2][col] + smAcc[3][b2][col];
    agg[((size_t)n * BB + b2) * 32 + col] = v2r;
}

// node MLP v7: wave per (b,n), 4 waves/block; reads agg; fused proj for t+1
__global__ __launch_bounds__(256) void node_mlp_v7(
    const float* __restrict__ agg,
    float* __restrict__ xn,
    const float* __restrict__ feature,
    const float* __restrict__ Wn, const float* __restrict__ bn,
    const float* __restrict__ W1, const float* __restrict__ b1,
    const float* __restrict__ W2, const float* __restrict__ b2,
    const float* __restrict__ W3, const float* __restrict__ b3,
    const float* __restrict__ Wo, const float* __restrict__ bo,
    const float* __restrict__ We1,
    const float* __restrict__ wind_mean, const float* __restrict__ wind_std,
    uint* __restrict__ Ps, uint* __restrict__ Pt,
    float* __restrict__ spd3, float* __restrict__ wdirA,
    float* __restrict__ out, int t) {
    int wid  = threadIdx.x >> 6;
    int lane = threadIdx.x & 63;
    int i = blockIdx.x * 4 + wid;        // grid exact: BB*NN/4
    int b = i / NN, n = i % NN;
    int ht = HIST + t;

    __shared__ float smAgg[4][33];
    __shared__ float smHin[4][28];
    __shared__ float smH[4][HID];

    if (lane < 32) smAgg[wid][lane] = agg[((size_t)n * BB + b) * 32 + lane];
    __syncthreads();

    const float* fr = feature + ((size_t)(b * TSTEPS + ht) * NN + n) * FEAT;
    if (lane < GNN_OUT) {
        float g = bn[lane];
#pragma unroll
        for (int k = 0; k < EOUT; ++k)
            g = fmaf(smAgg[wid][k], Wn[k * GNN_OUT + lane], g);
        smHin[wid][lane] = sigmoidf_(g);
    } else if (lane < GNN_OUT + IN_DIM) {
        smHin[wid][lane] = (lane == GNN_OUT) ? xn[i] : fr[lane - GNN_OUT - 1];
    }
    __syncthreads();

    // layer 1: 27 -> 64
    float v = b1[lane];
#pragma unroll
    for (int k = 0; k < GNN_OUT + IN_DIM; ++k)
        v = fmaf(smHin[wid][k], W1[k * HID + lane], v);
    float hval = sigmoidf_(v);
    smH[wid][lane] = hval;
    __syncthreads();

    // layer 2
    v = b2[lane];
#pragma unroll
    for (int k = 0; k < HID; ++k)
        v = fmaf(smH[wid][k], W2[k * HID + lane], v);
    hval = sigmoidf_(v);
    __syncthreads();
    smH[wid][lane] = hval;
    __syncthreads();

    // layer 3
    v = b3[lane];
#pragma unroll
    for (int k = 0; k < HID; ++k)
        v = fmaf(smH[wid][k], W3[k * HID + lane], v);
    hval = sigmoidf_(v);

    float partial = hval * Wo[lane];
#pragma unroll
    for (int m = 32; m >= 1; m >>= 1)
        partial += __shfl_xor(partial, m);
    float rr = partial + bo[0];
    if (lane == 0) {
        out[((size_t)(b * PRED + t)) * NN + n] = rr;
        xn[i] = rr;
    }

    // fused proj for step t+1 ([n][b] layout)
    if (t < PRED - 1) {
        const float* fr2 = feature + ((size_t)(b * TSTEPS + ht + 1) * NN + n) * FEAT;
        float xv[IN_DIM];
        xv[0] = rr;
#pragma unroll
        for (int f = 0; f < FEAT; ++f) xv[1 + f] = fr2[f];
        int j = lane & 31;
        int rowbase = (lane < 32) ? 0 : IN_DIM;
        float p = 0.0f;
#pragma unroll
        for (int f = 0; f < IN_DIM; ++f)
            p = fmaf(xv[f], We1[(rowbase + f) * EH + j], p);
        float pp = __shfl_xor(p, 1);
        if (!(j & 1)) {
            uint packed = pack2(p, pp);
            uint* dst = (lane < 32 ? Ps : Pt) + ((size_t)n * BB + b) * 16;
            dst[j >> 1] = packed;
        }
        if (lane == 0) {
            spd3[n * BB + b]  = 3.0f * fmaf(xv[12], wind_std[0], wind_mean[0]);
            wdirA[n * BB + b] = fmaf(xv[13], wind_std[1], wind_mean[1]);
        }
    }
}

// ================= v2 path (smallest-ws fallback, [b][p] layout) =============
__device__ __forceinline__ void compute_edge(
    int b, int e, int t,
    const float* __restrict__ xn, const float* __restrict__ feature,
    const float* __restrict__ edge_attr, const int* __restrict__ edge_index,
    const float* __restrict__ stats,
    const float* __restrict__ wind_mean, const float* __restrict__ wind_std,
    const float* __restrict__ We1, const float* __restrict__ be1,
    const float* __restrict__ We2, const float* __restrict__ be2,
    float* __restrict__ o) {
    int s  = edge_index[e];
    int tg = edge_index[NE + e];
    int ht = HIST + t;
    const float* fs  = feature + ((size_t)(b * TSTEPS + ht) * NN + s)  * FEAT;
    const float* ftg = feature + ((size_t)(b * TSTEPS + ht) * NN + tg) * FEAT;
    float ev[EIN];
    ev[0] = xn[b * NN + s];
#pragma unroll
    for (int f = 0; f < FEAT; ++f) ev[1 + f] = fs[f];
    ev[14] = xn[b * NN + tg];
#pragma unroll
    for (int f = 0; f < FEAT; ++f) ev[15 + f] = ftg[f];
    float dist  = edge_attr[2 * e];
    float direc = edge_attr[2 * e + 1];
    ev[28] = (dist  - stats[0]) * stats[1];
    ev[29] = (direc - stats[2]) * stats[3];
    float speed = ev[12] * wind_std[0] + wind_mean[0];
    float wdir  = ev[13] * wind_std[1] + wind_mean[1];
    float theta = fabsf(direc - wdir);
    float ew    = 3.0f * speed * cosf(theta) / dist;
    ev[30] = fmaxf(ew, 0.0f);
    float h[EH];
#pragma unroll
    for (int j = 0; j < EH; ++j) h[j] = be1[j];
#pragma unroll
    for (int i = 0; i < EIN; ++i) {
        float x = ev[i];
#pragma unroll
        for (int j = 0; j < EH; ++j) h[j] = fmaf(x, We1[i * EH + j], h[j]);
    }
#pragma unroll
    for (int j = 0; j < EH; ++j) h[j] = sigmoidf_(h[j]);
#pragma unroll
    for (int j = 0; j < EOUT; ++j) o[j] = be2[j];
#pragma unroll
    for (int i = 0; i < EH; ++i) {
        float x = h[i];
#pragma unroll
        for (int j = 0; j < EOUT; ++j) o[j] = fmaf(x, We2[i * EOUT + j], o[j]);
    }
}

__global__ __launch_bounds__(256) void edge_kernel_v2(
    const float* __restrict__ xn, const float* __restrict__ feature,
    const float* __restrict__ edge_attr, const int* __restrict__ edge_index,
    const float* __restrict__ stats,
    const float* __restrict__ wind_mean, const float* __restrict__ wind_std,
    const float* __restrict__ We1, const float* __restrict__ be1,
    const float* __restrict__ We2, const float* __restrict__ be2,
    const int* __restrict__ posT,
    ushort* __restrict__ e_out, int t) {
    int e = blockIdx.x * 256 + threadIdx.x;
    if (e >= NE) return;
    int b = blockIdx.y;
    float o[EOUT];
    compute_edge(b, e, t, xn, feature, edge_attr, edge_index, stats,
                 wind_mean, wind_std, We1, be1, We2, be2, o);
    uint w[16];
#pragma unroll
    for (int j = 0; j < 15; ++j)
        w[j] = pack2(sigmoidf_(o[2 * j]), sigmoidf_(o[2 * j + 1]));
    w[15] = 0u;
    int row = posT[e];
    uint4* dst = (uint4*)(e_out + ((size_t)b * NE + (size_t)row) * EOUT_PAD);
    dst[0] = make_uint4(w[0],  w[1],  w[2],  w[3]);
    dst[1] = make_uint4(w[4],  w[5],  w[6],  w[7]);
    dst[2] = make_uint4(w[8],  w[9],  w[10], w[11]);
    dst[3] = make_uint4(w[12], w[13], w[14], w[15]);
}

__global__ __launch_bounds__(256) void node_kernel_v2(
    const ushort* __restrict__ e_out,
    const int* __restrict__ offT, const int* __restrict__ offS,
    const int* __restrict__ listS_pos,
    float* __restrict__ xn,
    const float* __restrict__ feature,
    const float* __restrict__ Wn, const float* __restrict__ bn,
    const float* __restrict__ W1, const float* __restrict__ b1,
    const float* __restrict__ W2, const float* __restrict__ b2,
    const float* __restrict__ W3, const float* __restrict__ b3,
    const float* __restrict__ Wo, const float* __restrict__ bo,
    float* __restrict__ out, int t) {
    int i = blockIdx.x * 256 + threadIdx.x;
    if (i >= BB * NN) return;
    int b = i / NN, n = i % NN;
    int ht = HIST + t;
    const ushort* base = e_out + (size_t)b * NE * EOUT_PAD;
    float agg[EOUT];
#pragma unroll
    for (int j = 0; j < EOUT; ++j) agg[j] = 0.0f;
    int k0 = offT[n], k1 = offT[n + 1];
    for (int k = k0; k < k1; ++k) {
        const ushort* rr = base + (size_t)k * EOUT_PAD;
#pragma unroll
        for (int j = 0; j < EOUT; ++j) agg[j] += bf2f(rr[j]);
    }
    int q0 = offS[n], q1 = offS[n + 1];
    for (int k = q0; k < q1; ++k) {
        const ushort* rr = base + (size_t)listS_pos[k] * EOUT_PAD;
#pragma unroll
        for (int j = 0; j < EOUT; ++j) agg[j] -= bf2f(rr[j]);
    }
    float g[GNN_OUT];
#pragma unroll
    for (int j = 0; j < GNN_OUT; ++j) g[j] = bn[j];
#pragma unroll
    for (int k = 0; k < EOUT; ++k) {
        float x = agg[k];
#pragma unroll
        for (int j = 0; j < GNN_OUT; ++j) g[j] = fmaf(x, Wn[k * GNN_OUT + j], g[j]);
    }
    float hin[GNN_OUT + IN_DIM];
#pragma unroll
    for (int j = 0; j < GNN_OUT; ++j) hin[j] = sigmoidf_(g[j]);
    hin[GNN_OUT] = xn[i];
    const float* fr = feature + ((size_t)(b * TSTEPS + ht) * NN + n) * FEAT;
#pragma unroll
    for (int f = 0; f < FEAT; ++f) hin[GNN_OUT + 1 + f] = fr[f];
    float h1[HID];
#pragma unroll
    for (int j = 0; j < HID; ++j) h1[j] = b1[j];
#pragma unroll
    for (int k = 0; k < GNN_OUT + IN_DIM; ++k) {
        float x = hin[k];
#pragma unroll
        for (int j = 0; j < HID; ++j) h1[j] = fmaf(x, W1[k * HID + j], h1[j]);
    }
#pragma unroll
    for (int j = 0; j < HID; ++j) h1[j] = sigmoidf_(h1[j]);
    float h2[HID];
#pragma unroll
    for (int j = 0; j < HID; ++j) h2[j] = b2[j];
#pragma unroll
    for (int k = 0; k < HID; ++k) {
        float x = h1[k];
#pragma unroll
        for (int j = 0; j < HID; ++j) h2[j] = fmaf(x, W2[k * HID + j], h2[j]);
    }
#pragma unroll
    for (int j = 0; j < HID; ++j) h2[j] = sigmoidf_(h2[j]);
#pragma unroll
    for (int j = 0; j < HID; ++j) h1[j] = b3[j];
#pragma unroll
    for (int k = 0; k < HID; ++k) {
        float x = h2[k];
#pragma unroll
        for (int j = 0; j < HID; ++j) h1[j] = fmaf(x, W3[k * HID + j], h1[j]);
    }
    float acc = bo[0];
#pragma unroll
    for (int j = 0; j < HID; ++j) acc = fmaf(sigmoidf_(h1[j]), Wo[j], acc);
    out[((size_t)(b * PRED + t)) * NN + n] = acc;
    xn[i] = acc;
}

extern "C" void kernel_launch(void* const* d_in, const int* in_sizes, int n_in,
                              void* d_out, int out_size, void* d_ws, size_t ws_size,
                              hipStream_t stream) {
    const float* pm25      = (const float*)d_in[0];
    const float* feature   = (const float*)d_in[1];
    const float* edge_attr = (const float*)d_in[2];
    const float* wind_mean = (const float*)d_in[3];
    const float* wind_std  = (const float*)d_in[4];
    const float* We1 = (const float*)d_in[5];
    const float* be1 = (const float*)d_in[6];
    const float* We2 = (const float*)d_in[7];
    const float* be2 = (const float*)d_in[8];
    const float* Wn  = (const float*)d_in[9];
    const float* bn  = (const float*)d_in[10];
    const float* W1  = (const float*)d_in[11];
    const float* b1  = (const float*)d_in[12];
    const float* W2  = (const float*)d_in[13];
    const float* b2  = (const float*)d_in[14];
    const float* W3  = (const float*)d_in[15];
    const float* b3  = (const float*)d_in[16];
    const float* Wo  = (const float*)d_in[17];
    const float* bo  = (const float*)d_in[18];
    const int* edge_index = (const int*)d_in[19];
    float* out = (float*)d_out;

    char* ws = (char*)d_ws;
    size_t off = 0;
    auto alloc = [&](size_t bytes) {
        void* p = ws + off;
        off = (off + bytes + 255) & ~(size_t)255;
        return p;
    };
    float*  xn    = (float*)alloc((size_t)BB * NN * sizeof(float));
    float*  stats = (float*)alloc(4 * sizeof(float));
    double* part  = (double*)alloc(4 * SB * sizeof(double));
    int* degT      = (int*)alloc(NN * sizeof(int));
    int* degS      = (int*)alloc(NN * sizeof(int));
    int* offT      = (int*)alloc((NN + 1) * sizeof(int));
    int* offS      = (int*)alloc((NN + 1) * sizeof(int));
    int* curT      = (int*)alloc(NN * sizeof(int));
    int* curS      = (int*)alloc(NN * sizeof(int));
    int* posT      = (int*)alloc(NE * sizeof(int));
    int* listS_eid = (int*)alloc(NE * sizeof(int));
    int* listS_pos = (int*)alloc(NE * sizeof(int));
    size_t v2_mark = off;
    int*   srcT  = (int*)alloc(NE * sizeof(int));
    int*   tgT   = (int*)alloc(NE * sizeof(int));
    float* attrT = (float*)alloc(2 * NE * sizeof(float));
    uint*  Ce    = (uint*)alloc((size_t)NE * 16 * sizeof(uint));
    uint*  Ps    = (uint*)alloc((size_t)NN * BB * 16 * sizeof(uint));
    uint*  Pt    = (uint*)alloc((size_t)NN * BB * 16 * sizeof(uint));
    float* spd3  = (float*)alloc((size_t)NN * BB * sizeof(float));
    float* wdirA = (float*)alloc((size_t)NN * BB * sizeof(float));
    float* aggB  = (float*)alloc((size_t)NN * BB * 32 * sizeof(float));
    size_t base_off = off;
    size_t eout_bytes = (size_t)NE * BB * EOUT_PAD * sizeof(ushort);  // 65.5 MB

    bool v7 = (ws_size >= base_off + eout_bytes);
    ushort* e_out = v7 ? (ushort*)(ws + base_off) : (ushort*)(ws + v2_mark);

    stats_partial<<<SB, 256, 0, stream>>>(edge_attr, part);
    stats_final<<<1, 128, 0, stream>>>(part, stats);
    init_xn<<<(BB * NN + 255) / 256, 256, 0, stream>>>(pm25, xn);
    hipMemsetAsync(degT, 0, NN * sizeof(int), stream);
    hipMemsetAsync(degS, 0, NN * sizeof(int), stream);
    count_kernel<<<(NE + 255) / 256, 256, 0, stream>>>(edge_index, degT, degS);
    scan2_kernel<<<2, 256, 0, stream>>>(degT, degS, offT, offS, curT, curS);
    fill_kernel<<<(NE + 255) / 256, 256, 0, stream>>>(edge_index, curT, curS,
                                                      posT, listS_eid);
    map_kernel<<<(NE + 255) / 256, 256, 0, stream>>>(listS_eid, posT, listS_pos);

    if (v7) {
        sort_kernel<<<(NE + 255) / 256, 256, 0, stream>>>(edge_index, edge_attr, posT,
                                                          srcT, tgT, attrT);
        ce_kernel<<<(NE + 255) / 256, 256, 0, stream>>>(attrT, stats, We1, be1, Ce);
        proj0_kernel<<<(BB * NN + 255) / 256, 256, 0, stream>>>(
            xn, feature, We1, wind_mean, wind_std, Ps, Pt, spd3, wdirA);
        for (int t = 0; t < PRED; ++t) {
            edge_kernel_v6<<<NE / 16, 256, 0, stream>>>(Ps, Pt, Ce, We1, We2, be2,
                                                        srcT, tgT, attrT,
                                                        spd3, wdirA, e_out);
            agg_kernel<<<NN, 256, 0, stream>>>(e_out, offT, offS, listS_pos, aggB);
            node_mlp_v7<<<BB * NN / 4, 256, 0, stream>>>(
                aggB, xn, feature,
                Wn, bn, W1, b1, W2, b2, W3, b3, Wo, bo,
                We1, wind_mean, wind_std, Ps, Pt, spd3, wdirA, out, t);
        }
    } else {
        for (int t = 0; t < PRED; ++t) {
            dim3 eg((NE + 255) / 256, BB);
            edge_kernel_v2<<<eg, 256, 0, stream>>>(xn, feature, edge_attr, edge_index,
                                                   stats, wind_mean, wind_std,
                                                   We1, be1, We2, be2, posT, e_out, t);
            node_kernel_v2<<<(BB * NN + 255) / 256, 256, 0, stream>>>(
                e_out, offT, offS, listS_pos, xn, feature,
                Wn, bn, W1, b1, W2, b2, W3, b3, Wo, bo, out, t);
        }
    }
}

// Round 14
// 1707.716 us; speedup vs baseline: 3.0353x; 1.0117x over previous
//
#include <hip/hip_runtime.h>
#include <math.h>

#define BB 16
#define HIST 8
#define PRED 12
#define NN 2000
#define NE 64000
#define FEAT 13
#define IN_DIM 14   // FEAT+1
#define HID 64
#define GNN_OUT 13
#define EH 32
#define EOUT 30
#define EOUT_PAD 32
#define TSTEPS 20   // HIST+PRED
#define EIN 31      // 2*IN_DIM + 3
#define SB 128      // stats partial blocks

typedef unsigned int uint;
typedef unsigned short ushort;

__device__ __forceinline__ float sigmoidf_(float x) {
    return __builtin_amdgcn_rcpf(1.0f + __expf(-x));
}

__device__ __forceinline__ ushort f2bf(float x) {
    uint u = __float_as_uint(x);
    u += 0x7fffu + ((u >> 16) & 1u);
    return (ushort)(u >> 16);
}

__device__ __forceinline__ float bf2f(ushort u) {
    return __uint_as_float(((uint)u) << 16);
}

__device__ __forceinline__ float bflo(uint u) { return __uint_as_float(u << 16); }
__device__ __forceinline__ float bfhi(uint u) { return __uint_as_float(u & 0xffff0000u); }
__device__ __forceinline__ uint pack2(float a, float b) {
    return (uint)f2bf(a) | ((uint)f2bf(b) << 16);
}

// ---- stats ----
__global__ __launch_bounds__(256) void stats_partial(const float* __restrict__ edge_attr,
                                                     double* __restrict__ part) {
    __shared__ double sh[256];
    int tid = threadIdx.x, bid = blockIdx.x;
    double s0 = 0, q0 = 0, s1 = 0, q1 = 0;
    for (int i = bid * 256 + tid; i < NE; i += SB * 256) {
        double d = (double)edge_attr[2 * i];
        double r = (double)edge_attr[2 * i + 1];
        s0 += d; q0 += d * d; s1 += r; q1 += r * r;
    }
    double vals[4] = {s0, q0, s1, q1};
#pragma unroll
    for (int k = 0; k < 4; ++k) {
        sh[tid] = vals[k];
        __syncthreads();
        for (int off = 128; off > 0; off >>= 1) {
            if (tid < off) sh[tid] += sh[tid + off];
            __syncthreads();
        }
        if (tid == 0) part[k * SB + bid] = sh[0];
        __syncthreads();
    }
}

__global__ __launch_bounds__(128) void stats_final(const double* __restrict__ part,
                                                   float* __restrict__ stats) {
    __shared__ double sh[128];
    int tid = threadIdx.x;
    double res[4];
#pragma unroll
    for (int k = 0; k < 4; ++k) {
        sh[tid] = part[k * SB + tid];
        __syncthreads();
        for (int off = 64; off > 0; off >>= 1) {
            if (tid < off) sh[tid] += sh[tid + off];
            __syncthreads();
        }
        res[k] = sh[0];
        __syncthreads();
    }
    if (tid == 0) {
        double n = (double)NE;
        double m0 = res[0] / n, m1 = res[2] / n;
        double v0 = (res[1] - res[0] * res[0] / n) / (n - 1.0);
        double v1 = (res[3] - res[2] * res[2] / n) / (n - 1.0);
        stats[0] = (float)m0;
        stats[1] = (float)(1.0 / sqrt(v0));
        stats[2] = (float)m1;
        stats[3] = (float)(1.0 / sqrt(v1));
    }
}

__global__ void init_xn(const float* __restrict__ pm25,
                        float* __restrict__ xn) {
    int i = blockIdx.x * 256 + threadIdx.x;
    if (i >= BB * NN) return;
    int b = i / NN, n = i % NN;
    xn[i] = pm25[(b * HIST + (HIST - 1)) * NN + n];
}

// ---- CSR build ----
__global__ void count_kernel(const int* __restrict__ edge_index,
                             int* __restrict__ degT, int* __restrict__ degS) {
    int e = blockIdx.x * 256 + threadIdx.x;
    if (e >= NE) return;
    atomicAdd(&degT[edge_index[NE + e]], 1);
    atomicAdd(&degS[edge_index[e]], 1);
}

__global__ void scan2_kernel(const int* __restrict__ degT, const int* __restrict__ degS,
                             int* __restrict__ offT, int* __restrict__ offS,
                             int* __restrict__ curT, int* __restrict__ curS) {
    const int* deg = blockIdx.x ? degS : degT;
    int* off = blockIdx.x ? offS : offT;
    int* cur = blockIdx.x ? curS : curT;
    __shared__ int part[256];
    int tid = threadIdx.x;
    int base = tid * 8;
    int v[8]; int s = 0;
#pragma unroll
    for (int k = 0; k < 8; ++k) {
        int idx = base + k;
        int d = (idx < NN) ? deg[idx] : 0;
        v[k] = d; s += d;
    }
    part[tid] = s;
    __syncthreads();
    for (int offn = 1; offn < 256; offn <<= 1) {
        int x = part[tid];
        int y = (tid >= offn) ? part[tid - offn] : 0;
        __syncthreads();
        part[tid] = x + y;
        __syncthreads();
    }
    int run = (tid > 0) ? part[tid - 1] : 0;
#pragma unroll
    for (int k = 0; k < 8; ++k) {
        int idx = base + k;
        if (idx < NN) { off[idx] = run; cur[idx] = run; }
        run += v[k];
    }
    if (tid == 255) off[NN] = run;
}

__global__ void fill_kernel(const int* __restrict__ edge_index,
                            int* __restrict__ curT, int* __restrict__ curS,
                            int* __restrict__ posT, int* __restrict__ listS_eid) {
    int e = blockIdx.x * 256 + threadIdx.x;
    if (e >= NE) return;
    int tg = edge_index[NE + e], s = edge_index[e];
    int p = atomicAdd(&curT[tg], 1);
    posT[e] = p;
    int q = atomicAdd(&curS[s], 1);
    listS_eid[q] = e;
}

__global__ void map_kernel(const int* __restrict__ listS_eid,
                           const int* __restrict__ posT,
                           int* __restrict__ listS_pos) {
    int k = blockIdx.x * 256 + threadIdx.x;
    if (k >= NE) return;
    listS_pos[k] = posT[listS_eid[k]];
}

__global__ void sort_kernel(const int* __restrict__ edge_index,
                            const float* __restrict__ edge_attr,
                            const int* __restrict__ posT,
                            int* __restrict__ srcT, int* __restrict__ tgT,
                            float* __restrict__ attrT) {
    int e = blockIdx.x * 256 + threadIdx.x;
    if (e >= NE) return;
    int p = posT[e];
    srcT[p] = edge_index[e];
    tgT[p] = edge_index[NE + e];
    attrT[2 * p]     = edge_attr[2 * e];
    attrT[2 * p + 1] = edge_attr[2 * e + 1];
}

// Ce[p][32] (bf16x2 packed) = an0*We1[28] + an1*We1[29] + be1
__global__ void ce_kernel(const float* __restrict__ attrT,
                          const float* __restrict__ stats,
                          const float* __restrict__ We1,
                          const float* __restrict__ be1,
                          uint* __restrict__ Ce) {
    int p = blockIdx.x * 256 + threadIdx.x;
    if (p >= NE) return;
    float an0 = (attrT[2 * p]     - stats[0]) * stats[1];
    float an1 = (attrT[2 * p + 1] - stats[2]) * stats[3];
    float c[EH];
#pragma unroll
    for (int j = 0; j < EH; ++j)
        c[j] = fmaf(an0, We1[28 * EH + j], fmaf(an1, We1[29 * EH + j], be1[j]));
    uint* dst = Ce + (size_t)p * 16;
#pragma unroll
    for (int q = 0; q < 16; ++q) dst[q] = pack2(c[2 * q], c[2 * q + 1]);
}

// t=0 proj: Ps/Pt in [n][b] layout
__global__ __launch_bounds__(256) void proj0_kernel(
    const float* __restrict__ xn, const float* __restrict__ feature,
    const float* __restrict__ We1,
    const float* __restrict__ wind_mean, const float* __restrict__ wind_std,
    uint* __restrict__ Ps, uint* __restrict__ Pt,
    float* __restrict__ spd3, float* __restrict__ wdirA) {
    int i = blockIdx.x * 256 + threadIdx.x;
    if (i >= BB * NN) return;
    int b = i / NN, n = i % NN;
    float x[IN_DIM];
    x[0] = xn[i];
    const float* fr = feature + ((size_t)(b * TSTEPS + HIST) * NN + n) * FEAT;
#pragma unroll
    for (int f = 0; f < FEAT; ++f) x[1 + f] = fr[f];

    float ps[EH], pt[EH];
#pragma unroll
    for (int j = 0; j < EH; ++j) { ps[j] = 0.f; pt[j] = 0.f; }
#pragma unroll
    for (int f = 0; f < IN_DIM; ++f) {
        float xv = x[f];
#pragma unroll
        for (int j = 0; j < EH; ++j) {
            ps[j] = fmaf(xv, We1[f * EH + j], ps[j]);
            pt[j] = fmaf(xv, We1[(IN_DIM + f) * EH + j], pt[j]);
        }
    }
    uint* pso = Ps + ((size_t)n * BB + b) * 16;
    uint* pto = Pt + ((size_t)n * BB + b) * 16;
#pragma unroll
    for (int q = 0; q < 16; ++q) {
        pso[q] = pack2(ps[2 * q], ps[2 * q + 1]);
        pto[q] = pack2(pt[2 * q], pt[2 * q + 1]);
    }
    spd3[n * BB + b]  = 3.0f * fmaf(x[12], wind_std[0], wind_mean[0]);
    wdirA[n * BB + b] = fmaf(x[13], wind_std[1], wind_mean[1]);
}

// edge kernel v6: thread=(p,b); [p][b] e_out layout; all-b in one launch
__global__ __launch_bounds__(256) void edge_kernel_v6(
    const uint* __restrict__ Ps, const uint* __restrict__ Pt,
    const uint* __restrict__ Ce,
    const float* __restrict__ We1,
    const float* __restrict__ We2, const float* __restrict__ be2,
    const int* __restrict__ srcT, const int* __restrict__ tgT,
    const float* __restrict__ attrT,
    const float* __restrict__ spd3, const float* __restrict__ wdirA,
    ushort* __restrict__ e_out) {
    int tid = threadIdx.x;
    int b = tid & 15;
    int p = blockIdx.x * 16 + (tid >> 4);
    int s  = srcT[p];
    int tg = tgT[p];
    float dist  = attrT[2 * p];
    float direc = attrT[2 * p + 1];
    float sp3 = spd3[s * BB + b];
    float wd  = wdirA[s * BB + b];
    float theta = fabsf(direc - wd);
    float ew = fmaxf(sp3 * cosf(theta) * __builtin_amdgcn_rcpf(dist), 0.0f);

    const uint4* ps4 = (const uint4*)(Ps + ((size_t)s  * BB + b) * 16);
    const uint4* pt4 = (const uint4*)(Pt + ((size_t)tg * BB + b) * 16);
    const uint4* ce4 = (const uint4*)(Ce + (size_t)p * 16);

    float h[EH];
#pragma unroll
    for (int q = 0; q < 4; ++q) {
        uint4 a = ps4[q], c = pt4[q], d = ce4[q];
        uint av[4] = {a.x, a.y, a.z, a.w};
        uint cv[4] = {c.x, c.y, c.z, c.w};
        uint dv[4] = {d.x, d.y, d.z, d.w};
#pragma unroll
        for (int m = 0; m < 4; ++m) {
            int j = q * 8 + m * 2;
            h[j]     = bflo(av[m]) + bflo(cv[m]) + bflo(dv[m]);
            h[j + 1] = bfhi(av[m]) + bfhi(cv[m]) + bfhi(dv[m]);
        }
    }
#pragma unroll
    for (int j = 0; j < EH; ++j)
        h[j] = sigmoidf_(fmaf(ew, We1[30 * EH + j], h[j]));

    float o[EOUT];
#pragma unroll
    for (int j = 0; j < EOUT; ++j) o[j] = be2[j];
#pragma unroll
    for (int i = 0; i < EH; ++i) {
        float x = h[i];
#pragma unroll
        for (int j = 0; j < EOUT; ++j) o[j] = fmaf(x, We2[i * EOUT + j], o[j]);
    }

    uint w[16];
#pragma unroll
    for (int j = 0; j < 15; ++j)
        w[j] = pack2(sigmoidf_(o[2 * j]), sigmoidf_(o[2 * j + 1]));
    w[15] = 0u;
    uint4* dst = (uint4*)(e_out + ((size_t)p * BB + b) * EOUT_PAD);
    dst[0] = make_uint4(w[0],  w[1],  w[2],  w[3]);
    dst[1] = make_uint4(w[4],  w[5],  w[6],  w[7]);
    dst[2] = make_uint4(w[8],  w[9],  w[10], w[11]);
    dst[3] = make_uint4(w[12], w[13], w[14], w[15]);
}

// agg kernel: block per node n; coalesced 1KB-granule gather; writes agg[n][b][32]
__global__ __launch_bounds__(256) void agg_kernel(
    const ushort* __restrict__ e_out,
    const int* __restrict__ offT, const int* __restrict__ offS,
    const int* __restrict__ listS_pos,
    float* __restrict__ agg) {
    int n = blockIdx.x;
    int tid = threadIdx.x;
    int w = tid >> 6;        // wave 0..3
    int lane = tid & 63;
    int b = lane & 15;
    int c = lane >> 4;       // row quad (8 bf16 cols)

    const uint4* base4 = (const uint4*)e_out;

    float accA[8], accB[8];
#pragma unroll
    for (int i = 0; i < 8; ++i) { accA[i] = 0.f; accB[i] = 0.f; }

    int k0 = offT[n], k1 = offT[n + 1];
    int k = k0 + w;
    for (; k + 4 < k1; k += 8) {
        uint4 v0 = base4[((size_t)k       * BB + b) * 4 + c];
        uint4 v1 = base4[((size_t)(k + 4) * BB + b) * 4 + c];
        uint a0[4] = {v0.x, v0.y, v0.z, v0.w};
        uint a1[4] = {v1.x, v1.y, v1.z, v1.w};
#pragma unroll
        for (int m = 0; m < 4; ++m) {
            accA[2 * m]     += bflo(a0[m]);
            accA[2 * m + 1] += bfhi(a0[m]);
            accB[2 * m]     += bflo(a1[m]);
            accB[2 * m + 1] += bfhi(a1[m]);
        }
    }
    for (; k < k1; k += 4) {
        uint4 v0 = base4[((size_t)k * BB + b) * 4 + c];
        uint a0[4] = {v0.x, v0.y, v0.z, v0.w};
#pragma unroll
        for (int m = 0; m < 4; ++m) {
            accA[2 * m]     += bflo(a0[m]);
            accA[2 * m + 1] += bfhi(a0[m]);
        }
    }
    int q0 = offS[n], q1 = offS[n + 1];
    k = q0 + w;
    for (; k + 4 < q1; k += 8) {
        int r0 = listS_pos[k];
        int r1 = listS_pos[k + 4];
        uint4 v0 = base4[((size_t)r0 * BB + b) * 4 + c];
        uint4 v1 = base4[((size_t)r1 * BB + b) * 4 + c];
        uint a0[4] = {v0.x, v0.y, v0.z, v0.w};
        uint a1[4] = {v1.x, v1.y, v1.z, v1.w};
#pragma unroll
        for (int m = 0; m < 4; ++m) {
            accA[2 * m]     -= bflo(a0[m]);
            accA[2 * m + 1] -= bfhi(a0[m]);
            accB[2 * m]     -= bflo(a1[m]);
            accB[2 * m + 1] -= bfhi(a1[m]);
        }
    }
    for (; k < q1; k += 4) {
        int r0 = listS_pos[k];
        uint4 v0 = base4[((size_t)r0 * BB + b) * 4 + c];
        uint a0[4] = {v0.x, v0.y, v0.z, v0.w};
#pragma unroll
        for (int m = 0; m < 4; ++m) {
            accA[2 * m]     -= bflo(a0[m]);
            accA[2 * m + 1] -= bfhi(a0[m]);
        }
    }

    __shared__ float smAcc[4][16][36];   // pad 36: <=2-way bank alias
#pragma unroll
    for (int i = 0; i < 8; ++i) smAcc[w][b][c * 8 + i] = accA[i] + accB[i];
    __syncthreads();

    int col = tid & 31, bb = tid >> 5;   // bb 0..7
    float v1r = smAcc[0][bb][col] + smAcc[1][bb][col]
              + smAcc[2][bb][col] + smAcc[3][bb][col];
    agg[((size_t)n * BB + bb) * 32 + col] = v1r;
    int b2 = bb + 8;
    float v2r = smAcc[0][b2][col] + smAcc[1][b2][col]
              + smAcc[2][b2][col] + smAcc[3][b2][col];
    agg[((size_t)n * BB + b2) * 32 + col] = v2r;
}

// node MLP v8: wave per (b,n), 4 waves/block; 4-way ILP accumulators
__global__ __launch_bounds__(256) void node_mlp_v8(
    const float* __restrict__ agg,
    float* __restrict__ xn,
    const float* __restrict__ feature,
    const float* __restrict__ Wn, const float* __restrict__ bn,
    const float* __restrict__ W1, const float* __restrict__ b1,
    const float* __restrict__ W2, const float* __restrict__ b2,
    const float* __restrict__ W3, const float* __restrict__ b3,
    const float* __restrict__ Wo, const float* __restrict__ bo,
    const float* __restrict__ We1,
    const float* __restrict__ wind_mean, const float* __restrict__ wind_std,
    uint* __restrict__ Ps, uint* __restrict__ Pt,
    float* __restrict__ spd3, float* __restrict__ wdirA,
    float* __restrict__ out, int t) {
    int wid  = threadIdx.x >> 6;
    int lane = threadIdx.x & 63;
    int i = blockIdx.x * 4 + wid;        // grid exact: BB*NN/4
    int b = i / NN, n = i % NN;
    int ht = HIST + t;

    __shared__ float smAgg[4][33];
    __shared__ float smHin[4][28];
    __shared__ float smH[4][HID];

    if (lane < 32) smAgg[wid][lane] = agg[((size_t)n * BB + b) * 32 + lane];
    __syncthreads();

    const float* fr = feature + ((size_t)(b * TSTEPS + ht) * NN + n) * FEAT;
    if (lane < GNN_OUT) {
        // gnn head: 30 iters, 2-way ILP
        float g0 = 0.f, g1 = 0.f;
#pragma unroll
        for (int k = 0; k < EOUT; k += 2) {
            g0 = fmaf(smAgg[wid][k],     Wn[k * GNN_OUT + lane],       g0);
            g1 = fmaf(smAgg[wid][k + 1], Wn[(k + 1) * GNN_OUT + lane], g1);
        }
        smHin[wid][lane] = sigmoidf_(bn[lane] + g0 + g1);
    } else if (lane < GNN_OUT + IN_DIM) {
        smHin[wid][lane] = (lane == GNN_OUT) ? xn[i] : fr[lane - GNN_OUT - 1];
    }
    __syncthreads();

    // layer 1: 27 -> 64, 4-way ILP (24 + 3 tail)
    float v0 = 0.f, v1 = 0.f, v2 = 0.f, v3 = 0.f;
#pragma unroll
    for (int k = 0; k < 24; k += 4) {
        v0 = fmaf(smHin[wid][k],     W1[k * HID + lane],       v0);
        v1 = fmaf(smHin[wid][k + 1], W1[(k + 1) * HID + lane], v1);
        v2 = fmaf(smHin[wid][k + 2], W1[(k + 2) * HID + lane], v2);
        v3 = fmaf(smHin[wid][k + 3], W1[(k + 3) * HID + lane], v3);
    }
    v0 = fmaf(smHin[wid][24], W1[24 * HID + lane], v0);
    v1 = fmaf(smHin[wid][25], W1[25 * HID + lane], v1);
    v2 = fmaf(smHin[wid][26], W1[26 * HID + lane], v2);
    float hval = sigmoidf_(b1[lane] + ((v0 + v1) + (v2 + v3)));
    smH[wid][lane] = hval;
    __syncthreads();

    // layer 2: 64 -> 64, 4-way ILP
    v0 = 0.f; v1 = 0.f; v2 = 0.f; v3 = 0.f;
#pragma unroll
    for (int k = 0; k < HID; k += 4) {
        v0 = fmaf(smH[wid][k],     W2[k * HID + lane],       v0);
        v1 = fmaf(smH[wid][k + 1], W2[(k + 1) * HID + lane], v1);
        v2 = fmaf(smH[wid][k + 2], W2[(k + 2) * HID + lane], v2);
        v3 = fmaf(smH[wid][k + 3], W2[(k + 3) * HID + lane], v3);
    }
    hval = sigmoidf_(b2[lane] + ((v0 + v1) + (v2 + v3)));
    __syncthreads();
    smH[wid][lane] = hval;
    __syncthreads();

    // layer 3: 64 -> 64, 4-way ILP
    v0 = 0.f; v1 = 0.f; v2 = 0.f; v3 = 0.f;
#pragma unroll
    for (int k = 0; k < HID; k += 4) {
        v0 = fmaf(smH[wid][k],     W3[k * HID + lane],       v0);
        v1 = fmaf(smH[wid][k + 1], W3[(k + 1) * HID + lane], v1);
        v2 = fmaf(smH[wid][k + 2], W3[(k + 2) * HID + lane], v2);
        v3 = fmaf(smH[wid][k + 3], W3[(k + 3) * HID + lane], v3);
    }
    hval = sigmoidf_(b3[lane] + ((v0 + v1) + (v2 + v3)));

    float partial = hval * Wo[lane];
#pragma unroll
    for (int m = 32; m >= 1; m >>= 1)
        partial += __shfl_xor(partial, m);
    float rr = partial + bo[0];
    if (lane == 0) {
        out[((size_t)(b * PRED + t)) * NN + n] = rr;
        xn[i] = rr;
    }

    // fused proj for step t+1 ([n][b] layout), 2-way ILP
    if (t < PRED - 1) {
        const float* fr2 = feature + ((size_t)(b * TSTEPS + ht + 1) * NN + n) * FEAT;
        float xv[IN_DIM];
        xv[0] = rr;
#pragma unroll
        for (int f = 0; f < FEAT; ++f) xv[1 + f] = fr2[f];
        int j = lane & 31;
        int rowbase = (lane < 32) ? 0 : IN_DIM;
        float p0 = 0.0f, p1 = 0.0f;
#pragma unroll
        for (int f = 0; f < IN_DIM; f += 2) {
            p0 = fmaf(xv[f],     We1[(rowbase + f) * EH + j],     p0);
            p1 = fmaf(xv[f + 1], We1[(rowbase + f + 1) * EH + j], p1);
        }
        float p = p0 + p1;
        float pp = __shfl_xor(p, 1);
        if (!(j & 1)) {
            uint packed = pack2(p, pp);
            uint* dst = (lane < 32 ? Ps : Pt) + ((size_t)n * BB + b) * 16;
            dst[j >> 1] = packed;
        }
        if (lane == 0) {
            spd3[n * BB + b]  = 3.0f * fmaf(xv[12], wind_std[0], wind_mean[0]);
            wdirA[n * BB + b] = fmaf(xv[13], wind_std[1], wind_mean[1]);
        }
    }
}

// ================= v2 path (smallest-ws fallback, [b][p] layout) =============
__device__ __forceinline__ void compute_edge(
    int b, int e, int t,
    const float* __restrict__ xn, const float* __restrict__ feature,
    const float* __restrict__ edge_attr, const int* __restrict__ edge_index,
    const float* __restrict__ stats,
    const float* __restrict__ wind_mean, const float* __restrict__ wind_std,
    const float* __restrict__ We1, const float* __restrict__ be1,
    const float* __restrict__ We2, const float* __restrict__ be2,
    float* __restrict__ o) {
    int s  = edge_index[e];
    int tg = edge_index[NE + e];
    int ht = HIST + t;
    const float* fs  = feature + ((size_t)(b * TSTEPS + ht) * NN + s)  * FEAT;
    const float* ftg = feature + ((size_t)(b * TSTEPS + ht) * NN + tg) * FEAT;
    float ev[EIN];
    ev[0] = xn[b * NN + s];
#pragma unroll
    for (int f = 0; f < FEAT; ++f) ev[1 + f] = fs[f];
    ev[14] = xn[b * NN + tg];
#pragma unroll
    for (int f = 0; f < FEAT; ++f) ev[15 + f] = ftg[f];
    float dist  = edge_attr[2 * e];
    float direc = edge_attr[2 * e + 1];
    ev[28] = (dist  - stats[0]) * stats[1];
    ev[29] = (direc - stats[2]) * stats[3];
    float speed = ev[12] * wind_std[0] + wind_mean[0];
    float wdir  = ev[13] * wind_std[1] + wind_mean[1];
    float theta = fabsf(direc - wdir);
    float ew    = 3.0f * speed * cosf(theta) / dist;
    ev[30] = fmaxf(ew, 0.0f);
    float h[EH];
#pragma unroll
    for (int j = 0; j < EH; ++j) h[j] = be1[j];
#pragma unroll
    for (int i = 0; i < EIN; ++i) {
        float x = ev[i];
#pragma unroll
        for (int j = 0; j < EH; ++j) h[j] = fmaf(x, We1[i * EH + j], h[j]);
    }
#pragma unroll
    for (int j = 0; j < EH; ++j) h[j] = sigmoidf_(h[j]);
#pragma unroll
    for (int j = 0; j < EOUT; ++j) o[j] = be2[j];
#pragma unroll
    for (int i = 0; i < EH; ++i) {
        float x = h[i];
#pragma unroll
        for (int j = 0; j < EOUT; ++j) o[j] = fmaf(x, We2[i * EOUT + j], o[j]);
    }
}

__global__ __launch_bounds__(256) void edge_kernel_v2(
    const float* __restrict__ xn, const float* __restrict__ feature,
    const float* __restrict__ edge_attr, const int* __restrict__ edge_index,
    const float* __restrict__ stats,
    const float* __restrict__ wind_mean, const float* __restrict__ wind_std,
    const float* __restrict__ We1, const float* __restrict__ be1,
    const float* __restrict__ We2, const float* __restrict__ be2,
    const int* __restrict__ posT,
    ushort* __restrict__ e_out, int t) {
    int e = blockIdx.x * 256 + threadIdx.x;
    if (e >= NE) return;
    int b = blockIdx.y;
    float o[EOUT];
    compute_edge(b, e, t, xn, feature, edge_attr, edge_index, stats,
                 wind_mean, wind_std, We1, be1, We2, be2, o);
    uint w[16];
#pragma unroll
    for (int j = 0; j < 15; ++j)
        w[j] = pack2(sigmoidf_(o[2 * j]), sigmoidf_(o[2 * j + 1]));
    w[15] = 0u;
    int row = posT[e];
    uint4* dst = (uint4*)(e_out + ((size_t)b * NE + (size_t)row) * EOUT_PAD);
    dst[0] = make_uint4(w[0],  w[1],  w[2],  w[3]);
    dst[1] = make_uint4(w[4],  w[5],  w[6],  w[7]);
    dst[2] = make_uint4(w[8],  w[9],  w[10], w[11]);
    dst[3] = make_uint4(w[12], w[13], w[14], w[15]);
}

__global__ __launch_bounds__(256) void node_kernel_v2(
    const ushort* __restrict__ e_out,
    const int* __restrict__ offT, const int* __restrict__ offS,
    const int* __restrict__ listS_pos,
    float* __restrict__ xn,
    const float* __restrict__ feature,
    const float* __restrict__ Wn, const float* __restrict__ bn,
    const float* __restrict__ W1, const float* __restrict__ b1,
    const float* __restrict__ W2, const float* __restrict__ b2,
    const float* __restrict__ W3, const float* __restrict__ b3,
    const float* __restrict__ Wo, const float* __restrict__ bo,
    float* __restrict__ out, int t) {
    int i = blockIdx.x * 256 + threadIdx.x;
    if (i >= BB * NN) return;
    int b = i / NN, n = i % NN;
    int ht = HIST + t;
    const ushort* base = e_out + (size_t)b * NE * EOUT_PAD;
    float agg[EOUT];
#pragma unroll
    for (int j = 0; j < EOUT; ++j) agg[j] = 0.0f;
    int k0 = offT[n], k1 = offT[n + 1];
    for (int k = k0; k < k1; ++k) {
        const ushort* rr = base + (size_t)k * EOUT_PAD;
#pragma unroll
        for (int j = 0; j < EOUT; ++j) agg[j] += bf2f(rr[j]);
    }
    int q0 = offS[n], q1 = offS[n + 1];
    for (int k = q0; k < q1; ++k) {
        const ushort* rr = base + (size_t)listS_pos[k] * EOUT_PAD;
#pragma unroll
        for (int j = 0; j < EOUT; ++j) agg[j] -= bf2f(rr[j]);
    }
    float g[GNN_OUT];
#pragma unroll
    for (int j = 0; j < GNN_OUT; ++j) g[j] = bn[j];
#pragma unroll
    for (int k = 0; k < EOUT; ++k) {
        float x = agg[k];
#pragma unroll
        for (int j = 0; j < GNN_OUT; ++j) g[j] = fmaf(x, Wn[k * GNN_OUT + j], g[j]);
    }
    float hin[GNN_OUT + IN_DIM];
#pragma unroll
    for (int j = 0; j < GNN_OUT; ++j) hin[j] = sigmoidf_(g[j]);
    hin[GNN_OUT] = xn[i];
    const float* fr = feature + ((size_t)(b * TSTEPS + ht) * NN + n) * FEAT;
#pragma unroll
    for (int f = 0; f < FEAT; ++f) hin[GNN_OUT + 1 + f] = fr[f];
    float h1[HID];
#pragma unroll
    for (int j = 0; j < HID; ++j) h1[j] = b1[j];
#pragma unroll
    for (int k = 0; k < GNN_OUT + IN_DIM; ++k) {
        float x = hin[k];
#pragma unroll
        for (int j = 0; j < HID; ++j) h1[j] = fmaf(x, W1[k * HID + j], h1[j]);
    }
#pragma unroll
    for (int j = 0; j < HID; ++j) h1[j] = sigmoidf_(h1[j]);
    float h2[HID];
#pragma unroll
    for (int j = 0; j < HID; ++j) h2[j] = b2[j];
#pragma unroll
    for (int k = 0; k < HID; ++k) {
        float x = h1[k];
#pragma unroll
        for (int j = 0; j < HID; ++j) h2[j] = fmaf(x, W2[k * HID + j], h2[j]);
    }
#pragma unroll
    for (int j = 0; j < HID; ++j) h2[j] = sigmoidf_(h2[j]);
#pragma unroll
    for (int j = 0; j < HID; ++j) h1[j] = b3[j];
#pragma unroll
    for (int k = 0; k < HID; ++k) {
        float x = h2[k];
#pragma unroll
        for (int j = 0; j < HID; ++j) h1[j] = fmaf(x, W3[k * HID + j], h1[j]);
    }
    float acc = bo[0];
#pragma unroll
    for (int j = 0; j < HID; ++j) acc = fmaf(sigmoidf_(h1[j]), Wo[j], acc);
    out[((size_t)(b * PRED + t)) * NN + n] = acc;
    xn[i] = acc;
}

extern "C" void kernel_launch(void* const* d_in, const int* in_sizes, int n_in,
                              void* d_out, int out_size, void* d_ws, size_t ws_size,
                              hipStream_t stream) {
    const float* pm25      = (const float*)d_in[0];
    const float* feature   = (const float*)d_in[1];
    const float* edge_attr = (const float*)d_in[2];
    const float* wind_mean = (const float*)d_in[3];
    const float* wind_std  = (const float*)d_in[4];
    const float* We1 = (const float*)d_in[5];
    const float* be1 = (const float*)d_in[6];
    const float* We2 = (const float*)d_in[7];
    const float* be2 = (const float*)d_in[8];
    const float* Wn  = (const float*)d_in[9];
    const float* bn  = (const float*)d_in[10];
    const float* W1  = (const float*)d_in[11];
    const float* b1  = (const float*)d_in[12];
    const float* W2  = (const float*)d_in[13];
    const float* b2  = (const float*)d_in[14];
    const float* W3  = (const float*)d_in[15];
    const float* b3  = (const float*)d_in[16];
    const float* Wo  = (const float*)d_in[17];
    const float* bo  = (const float*)d_in[18];
    const int* edge_index = (const int*)d_in[19];
    float* out = (float*)d_out;

    char* ws = (char*)d_ws;
    size_t off = 0;
    auto alloc = [&](size_t bytes) {
        void* p = ws + off;
        off = (off + bytes + 255) & ~(size_t)255;
        return p;
    };
    float*  xn    = (float*)alloc((size_t)BB * NN * sizeof(float));
    float*  stats = (float*)alloc(4 * sizeof(float));
    double* part  = (double*)alloc(4 * SB * sizeof(double));
    int* degT      = (int*)alloc(NN * sizeof(int));
    int* degS      = (int*)alloc(NN * sizeof(int));
    int* offT      = (int*)alloc((NN + 1) * sizeof(int));
    int* offS      = (int*)alloc((NN + 1) * sizeof(int));
    int* curT      = (int*)alloc(NN * sizeof(int));
    int* curS      = (int*)alloc(NN * sizeof(int));
    int* posT      = (int*)alloc(NE * sizeof(int));
    int* listS_eid = (int*)alloc(NE * sizeof(int));
    int* listS_pos = (int*)alloc(NE * sizeof(int));
    size_t v2_mark = off;
    int*   srcT  = (int*)alloc(NE * sizeof(int));
    int*   tgT   = (int*)alloc(NE * sizeof(int));
    float* attrT = (float*)alloc(2 * NE * sizeof(float));
    uint*  Ce    = (uint*)alloc((size_t)NE * 16 * sizeof(uint));
    uint*  Ps    = (uint*)alloc((size_t)NN * BB * 16 * sizeof(uint));
    uint*  Pt    = (uint*)alloc((size_t)NN * BB * 16 * sizeof(uint));
    float* spd3  = (float*)alloc((size_t)NN * BB * sizeof(float));
    float* wdirA = (float*)alloc((size_t)NN * BB * sizeof(float));
    float* aggB  = (float*)alloc((size_t)NN * BB * 32 * sizeof(float));
    size_t base_off = off;
    size_t eout_bytes = (size_t)NE * BB * EOUT_PAD * sizeof(ushort);  // 65.5 MB

    bool v7 = (ws_size >= base_off + eout_bytes);
    ushort* e_out = v7 ? (ushort*)(ws + base_off) : (ushort*)(ws + v2_mark);

    stats_partial<<<SB, 256, 0, stream>>>(edge_attr, part);
    stats_final<<<1, 128, 0, stream>>>(part, stats);
    init_xn<<<(BB * NN + 255) / 256, 256, 0, stream>>>(pm25, xn);
    hipMemsetAsync(degT, 0, NN * sizeof(int), stream);
    hipMemsetAsync(degS, 0, NN * sizeof(int), stream);
    count_kernel<<<(NE + 255) / 256, 256, 0, stream>>>(edge_index, degT, degS);
    scan2_kernel<<<2, 256, 0, stream>>>(degT, degS, offT, offS, curT, curS);
    fill_kernel<<<(NE + 255) / 256, 256, 0, stream>>>(edge_index, curT, curS,
                                                      posT, listS_eid);
    map_kernel<<<(NE + 255) / 256, 256, 0, stream>>>(listS_eid, posT, listS_pos);

    if (v7) {
        sort_kernel<<<(NE + 255) / 256, 256, 0, stream>>>(edge_index, edge_attr, posT,
                                                          srcT, tgT, attrT);
        ce_kernel<<<(NE + 255) / 256, 256, 0, stream>>>(attrT, stats, We1, be1, Ce);
        proj0_kernel<<<(BB * NN + 255) / 256, 256, 0, stream>>>(
            xn, feature, We1, wind_mean, wind_std, Ps, Pt, spd3, wdirA);
        for (int t = 0; t < PRED; ++t) {
            edge_kernel_v6<<<NE / 16, 256, 0, stream>>>(Ps, Pt, Ce, We1, We2, be2,
                                                        srcT, tgT, attrT,
                                                        spd3, wdirA, e_out);
            agg_kernel<<<NN, 256, 0, stream>>>(e_out, offT, offS, listS_pos, aggB);
            node_mlp_v8<<<BB * NN / 4, 256, 0, stream>>>(
                aggB, xn, feature,
                Wn, bn, W1, b1, W2, b2, W3, b3, Wo, bo,
                We1, wind_mean, wind_std, Ps, Pt, spd3, wdirA, out, t);
        }
    } else {
        for (int t = 0; t < PRED; ++t) {
            dim3 eg((NE + 255) / 256, BB);
            edge_kernel_v2<<<eg, 256, 0, stream>>>(xn, feature, edge_attr, edge_index,
                                                   stats, wind_mean, wind_std,
                                                   We1, be1, We2, be2, posT, e_out, t);
            node_kernel_v2<<<(BB * NN + 255) / 256, 256, 0, stream>>>(
                e_out, offT, offS, listS_pos, xn, feature,
                Wn, bn, W1, b1, W2, b2, W3, b3, Wo, bo, out, t);
        }
    }
}